// Round 1
// baseline (2981.497 us; speedup 1.0000x reference)
//
#include <hip/hip_runtime.h>
#include <hip/hip_bf16.h>
#include <stdint.h>

#define NN 50000
#define EE 100000
#define DD 768
#define MP 50048   // 391 * 128
#define KIN 96     // 78 padded to 96

typedef __attribute__((ext_vector_type(8))) short v8s;
typedef __attribute__((ext_vector_type(4))) float v4f;

__device__ inline float b2f(unsigned short u){ return __uint_as_float(((unsigned)u)<<16); }
__device__ inline unsigned short f2b(float f){
  unsigned u = __float_as_uint(f);
  u += 0x7fffu + ((u>>16)&1u);
  return (unsigned short)(u>>16);
}

// ---------------- GEMM: C[M x 768] = A[M x K](bf16) * Bt[768 x K]^T (bf16) ----------------
// MODE 0: input proj  -> h32 = acc + bias; h16 = bf16(h32)
// MODE 1: conv        -> agg = acc*dinv[row]^2 + bias; xw16 = bf16(acc)
// MODE 2: out proj    -> o32 = acc + bias
template<int MODE>
__global__ __launch_bounds__(256)
void gemm_k(const unsigned short* __restrict__ A,
            const unsigned short* __restrict__ Bt,
            int K,
            const float* __restrict__ bias,
            const float* __restrict__ dinv,
            float* __restrict__ o32,
            unsigned short* __restrict__ o16,
            float* __restrict__ agg)
{
  __shared__ __align__(16) unsigned short As[128*32];
  __shared__ __align__(16) unsigned short Bs[128*32];
  const int m0 = blockIdx.x*128, n0 = blockIdx.y*128;
  const int t = threadIdx.x, l = t&63, w = t>>6;
  const int wr = w>>1, wc = w&1;
  v4f acc[4][4];
  #pragma unroll
  for (int i=0;i<4;++i)
    #pragma unroll
    for (int j=0;j<4;++j){ v4f z = {0.f,0.f,0.f,0.f}; acc[i][j]=z; }

  const int nkt = K/32;
  for (int kt=0; kt<nkt; ++kt){
    __syncthreads();
    #pragma unroll
    for (int i=0;i<2;++i){
      int c = i*256 + t;          // 0..511 chunk of 8 bf16
      int row = c>>2, ch = c&3;   // row 0..127, 4 chunks of 16B per row
      int sw = ch ^ ((row>>1)&3); // bank-conflict swizzle
      uint4 va = *(const uint4*)(A + (size_t)(m0+row)*K + kt*32 + ch*8);
      *(uint4*)(As + row*32 + sw*8) = va;
      uint4 vb = *(const uint4*)(Bt + (size_t)(n0+row)*K + kt*32 + ch*8);
      *(uint4*)(Bs + row*32 + sw*8) = vb;
    }
    __syncthreads();
    v8s af[4], bf[4];
    #pragma unroll
    for (int m=0;m<4;++m){
      int row = wr*64 + m*16 + (l&15);
      int ch = (l>>4) ^ ((row>>1)&3);
      af[m] = *(const v8s*)(As + row*32 + ch*8);
    }
    #pragma unroll
    for (int n=0;n<4;++n){
      int row = wc*64 + n*16 + (l&15);
      int ch = (l>>4) ^ ((row>>1)&3);
      bf[n] = *(const v8s*)(Bs + row*32 + ch*8);
    }
    #pragma unroll
    for (int m=0;m<4;++m)
      #pragma unroll
      for (int n=0;n<4;++n)
        acc[m][n] = __builtin_amdgcn_mfma_f32_16x16x32_bf16(af[m], bf[n], acc[m][n], 0,0,0);
  }

  #pragma unroll
  for (int m=0;m<4;++m){
    #pragma unroll
    for (int r=0;r<4;++r){
      int row = m0 + wr*64 + m*16 + (l>>4)*4 + r;
      if (row >= NN) continue;
      float sn = 0.f;
      if (MODE==1){ float dv = dinv[row]; sn = dv*dv; }
      #pragma unroll
      for (int n=0;n<4;++n){
        int col = n0 + wc*64 + n*16 + (l&15);
        float v = acc[m][n][r];
        size_t idx = (size_t)row*DD + col;
        if (MODE==0){
          float hv = v + bias[col];
          o32[idx] = hv;
          o16[idx] = f2b(hv);
        } else if (MODE==1){
          agg[idx] = fmaf(v, sn, bias[col]);
          o16[idx] = f2b(v);
        } else {
          o32[idx] = v + bias[col];
        }
      }
    }
  }
}

// ---------------- misc kernels ----------------
__global__ void k_count(const int* __restrict__ dst, int* __restrict__ cnt){
  int e = blockIdx.x*256 + threadIdx.x;
  if (e < EE) atomicAdd(&cnt[dst[e]], 1);
}
__global__ void k_dinv(const int* __restrict__ cnt, float* __restrict__ dinv){
  int i = blockIdx.x*256 + threadIdx.x;
  if (i < MP) dinv[i] = (i < NN) ? rsqrtf((float)cnt[i] + 1.0f) : 0.f;
}
__global__ void k_en(const int* __restrict__ src, const int* __restrict__ dst,
                     const float* __restrict__ dinv, float* __restrict__ en){
  int e = blockIdx.x*256 + threadIdx.x;
  if (e < EE) en[e] = dinv[src[e]]*dinv[dst[e]];
}
__global__ void k_x16(const float* __restrict__ x, unsigned short* __restrict__ x16){
  int idx = blockIdx.x*256 + threadIdx.x;
  if (idx < MP*KIN){
    int row = idx / KIN, k = idx - row*KIN;
    float v = (row < NN && k < 78) ? x[(size_t)row*78 + k] : 0.f;
    x16[idx] = f2b(v);
  }
}
// src [K x 768] fp32 -> dst [768 x ldk] bf16 (transposed, K-padded with zeros)
__global__ void k_tr(const float* __restrict__ src, unsigned short* __restrict__ dst, int K, int ldk){
  int idx = blockIdx.x*256 + threadIdx.x;
  if (idx < DD*ldk){
    int n = idx / ldk, k = idx - n*ldk;
    dst[idx] = (k < K) ? f2b(src[(size_t)k*DD + n]) : (unsigned short)0;
  }
}
__global__ void k_scatter(const int* __restrict__ src, const int* __restrict__ dst,
                          const float* __restrict__ en, const unsigned short* __restrict__ xw,
                          float* __restrict__ agg){
  int e = blockIdx.x;
  int s = src[e], d = dst[e];
  float wgt = en[e];
  const unsigned short* xr = xw + (size_t)s*DD;
  float* ar = agg + (size_t)d*DD;
  for (int c = threadIdx.x; c < DD; c += 256)
    atomicAdd(&ar[c], wgt * b2f(xr[c]));
}
__global__ void k_stats(const float* __restrict__ agg, float* __restrict__ sums, float* __restrict__ sumsq){
  int t = threadIdx.x;
  int r0 = blockIdx.x*256;
  int rend = min(r0+256, NN);
  float s0=0,s1=0,s2=0,q0=0,q1=0,q2=0;
  for (int r=r0; r<rend; ++r){
    const float* row = agg + (size_t)r*DD;
    float v0=row[t], v1=row[t+256], v2=row[t+512];
    s0+=v0; q0+=v0*v0; s1+=v1; q1+=v1*v1; s2+=v2; q2+=v2*v2;
  }
  atomicAdd(&sums[t],     s0); atomicAdd(&sums[t+256], s1); atomicAdd(&sums[t+512], s2);
  atomicAdd(&sumsq[t],    q0); atomicAdd(&sumsq[t+256],q1); atomicAdd(&sumsq[t+512],q2);
}
__global__ void k_final(const float* __restrict__ stats, const float* __restrict__ g,
                        const float* __restrict__ b, float* __restrict__ sc, float* __restrict__ sh){
  int t = threadIdx.x;
  #pragma unroll
  for (int j=0;j<3;++j){
    int d = t + j*256;
    float mu  = stats[d]      * (1.0f/NN);
    float msq = stats[DD+d]   * (1.0f/NN);
    float var = msq - mu*mu;
    float rstd = rsqrtf(var + 1e-5f);
    float scale = rstd * g[d];
    sc[d] = scale;
    sh[d] = b[d] - mu*scale;
  }
}
__global__ void k_apply(const float* __restrict__ agg, const float* __restrict__ sc,
                        const float* __restrict__ sh, float* __restrict__ h32,
                        unsigned short* __restrict__ h16){
  const int total = NN*DD/4;
  for (int i = blockIdx.x*blockDim.x + threadIdx.x; i < total; i += gridDim.x*blockDim.x){
    size_t base = (size_t)i*4;
    int col = (int)(base % DD);
    float4 a  = *(const float4*)(agg + base);
    float4 h  = *(const float4*)(h32 + base);
    float4 s  = *(const float4*)(sc + col);
    float4 t4 = *(const float4*)(sh + col);
    float o0 = h.x + fmaxf(fmaf(a.x, s.x, t4.x), 0.f);
    float o1 = h.y + fmaxf(fmaf(a.y, s.y, t4.y), 0.f);
    float o2 = h.z + fmaxf(fmaf(a.z, s.z, t4.z), 0.f);
    float o3 = h.w + fmaxf(fmaf(a.w, s.w, t4.w), 0.f);
    float4 ho = {o0,o1,o2,o3};
    *(float4*)(h32 + base) = ho;
    ushort4 hb = {f2b(o0), f2b(o1), f2b(o2), f2b(o3)};
    *(ushort4*)(h16 + base) = hb;
  }
}

extern "C" void kernel_launch(void* const* d_in, const int* in_sizes, int n_in,
                              void* d_out, int out_size, void* d_ws, size_t ws_size,
                              hipStream_t stream){
  (void)in_sizes; (void)n_in; (void)out_size; (void)ws_size;
  const float* x      = (const float*)d_in[0];
  const int*   ei     = (const int*)  d_in[1];
  const float* in_w   = (const float*)d_in[2];
  const float* in_b   = (const float*)d_in[3];
  const float* conv_w = (const float*)d_in[4];
  const float* conv_b = (const float*)d_in[5];
  const float* bn_g   = (const float*)d_in[6];
  const float* bn_b   = (const float*)d_in[7];
  const float* out_w  = (const float*)d_in[8];
  const float* out_b  = (const float*)d_in[9];
  float* out = (float*)d_out;
  const int* srcI = ei;
  const int* dstI = ei + EE;

  char* ws = (char*)d_ws; size_t off = 0;
  auto alloc = [&](size_t b)->void*{ void* p = ws + off; off += (b + 255) & ~(size_t)255; return p; };
  unsigned short* h16  = (unsigned short*)alloc((size_t)MP*DD*2);
  unsigned short* xw16 = (unsigned short*)alloc((size_t)MP*DD*2);
  float*          agg  = (float*)alloc((size_t)MP*DD*4);
  unsigned short* x16  = (unsigned short*)alloc((size_t)MP*KIN*2);
  unsigned short* wT   = (unsigned short*)alloc((size_t)(DD*KIN + 6*DD*DD)*2);
  float* dinv  = (float*)alloc((size_t)MP*4);
  int*   cnt   = (int*)  alloc((size_t)MP*4);
  float* en    = (float*)alloc((size_t)EE*4);
  float* stats = (float*)alloc((size_t)4*DD*4);
  float* h32 = out;  // d_out doubles as fp32 h (rows < NN only; overwritten by out proj at the end)

  unsigned short* wTin = wT;
  unsigned short* wTc  = wT + DD*KIN;
  unsigned short* wTo  = wTc + 5*DD*DD;

  hipMemsetAsync(cnt, 0, (size_t)MP*4, stream);
  hipMemsetAsync(h16 + (size_t)NN*DD, 0, (size_t)(MP-NN)*DD*2, stream);  // zero pad rows of h16
  k_count<<<(EE+255)/256,256,0,stream>>>(dstI, cnt);
  k_dinv <<<(MP+255)/256,256,0,stream>>>(cnt, dinv);
  k_en   <<<(EE+255)/256,256,0,stream>>>(srcI, dstI, dinv, en);
  k_x16  <<<(MP*KIN+255)/256,256,0,stream>>>(x, x16);
  k_tr   <<<(DD*KIN+255)/256,256,0,stream>>>(in_w, wTin, 78, KIN);
  for (int l = 0; l < 5; ++l)
    k_tr <<<(DD*DD+255)/256,256,0,stream>>>(conv_w + (size_t)l*DD*DD, wTc + (size_t)l*DD*DD, DD, DD);
  k_tr   <<<(DD*DD+255)/256,256,0,stream>>>(out_w, wTo, DD, DD);

  dim3 gg(MP/128, DD/128);
  gemm_k<0><<<gg,256,0,stream>>>(x16, wTin, KIN, in_b, nullptr, h32, h16, nullptr);

  for (int l = 0; l < 5; ++l){
    gemm_k<1><<<gg,256,0,stream>>>(h16, wTc + (size_t)l*DD*DD, DD, conv_b + l*DD, dinv, nullptr, xw16, agg);
    k_scatter<<<EE,256,0,stream>>>(srcI, dstI, en, xw16, agg);
    hipMemsetAsync(stats, 0, (size_t)2*DD*4, stream);
    k_stats<<<(NN+255)/256,256,0,stream>>>(agg, stats, stats+DD);
    k_final<<<1,256,0,stream>>>(stats, bn_g + l*DD, bn_b + l*DD, stats+2*DD, stats+3*DD);
    k_apply<<<2048,256,0,stream>>>(agg, stats+2*DD, stats+3*DD, h32, h16);
  }

  gemm_k<2><<<gg,256,0,stream>>>(h16, wTo, DD, out_b, nullptr, out, nullptr, nullptr);
}

// Round 2
// 1848.974 us; speedup vs baseline: 1.6125x; 1.6125x over previous
//
#include <hip/hip_runtime.h>
#include <hip/hip_bf16.h>
#include <stdint.h>

#define NN 50000
#define EE 100000
#define DD 768
#define MP 50048   // 391 * 128
#define KIN 96     // 78 padded to 96
#define SCB 196    // ceil(50000/256) scan blocks

typedef __attribute__((ext_vector_type(8))) short v8s;
typedef __attribute__((ext_vector_type(4))) float v4f;

__device__ inline float b2f(unsigned short u){ return __uint_as_float(((unsigned)u)<<16); }
__device__ inline unsigned short f2b(float f){
  unsigned u = __float_as_uint(f);
  u += 0x7fffu + ((u>>16)&1u);
  return (unsigned short)(u>>16);
}

// ---------------- GEMM: C[M x 768] = A[M x K](bf16) * Bt[768 x K]^T (bf16) ----------------
// MODE 0: input proj  -> h32 = acc + bias; h16 = bf16(h32)
// MODE 1: conv        -> xw16 = bf16(acc)          (bias/self-loop applied in gather)
// MODE 2: out proj    -> o32 = acc + bias
template<int MODE>
__global__ __launch_bounds__(256)
void gemm_k(const unsigned short* __restrict__ A,
            const unsigned short* __restrict__ Bt,
            int K,
            const float* __restrict__ bias,
            float* __restrict__ o32,
            unsigned short* __restrict__ o16)
{
  __shared__ __align__(16) unsigned short As[128*32];
  __shared__ __align__(16) unsigned short Bs[128*32];
  const int m0 = blockIdx.x*128, n0 = blockIdx.y*128;
  const int t = threadIdx.x, l = t&63, w = t>>6;
  const int wr = w>>1, wc = w&1;
  v4f acc[4][4];
  #pragma unroll
  for (int i=0;i<4;++i)
    #pragma unroll
    for (int j=0;j<4;++j){ v4f z = {0.f,0.f,0.f,0.f}; acc[i][j]=z; }

  const int nkt = K/32;
  for (int kt=0; kt<nkt; ++kt){
    __syncthreads();
    #pragma unroll
    for (int i=0;i<2;++i){
      int c = i*256 + t;          // 0..511 chunk of 8 bf16
      int row = c>>2, ch = c&3;   // row 0..127, 4 chunks of 16B per row
      int sw = ch ^ ((row>>1)&3); // bank-conflict swizzle
      uint4 va = *(const uint4*)(A + (size_t)(m0+row)*K + kt*32 + ch*8);
      *(uint4*)(As + row*32 + sw*8) = va;
      uint4 vb = *(const uint4*)(Bt + (size_t)(n0+row)*K + kt*32 + ch*8);
      *(uint4*)(Bs + row*32 + sw*8) = vb;
    }
    __syncthreads();
    v8s af[4], bf[4];
    #pragma unroll
    for (int m=0;m<4;++m){
      int row = wr*64 + m*16 + (l&15);
      int ch = (l>>4) ^ ((row>>1)&3);
      af[m] = *(const v8s*)(As + row*32 + ch*8);
    }
    #pragma unroll
    for (int n=0;n<4;++n){
      int row = wc*64 + n*16 + (l&15);
      int ch = (l>>4) ^ ((row>>1)&3);
      bf[n] = *(const v8s*)(Bs + row*32 + ch*8);
    }
    #pragma unroll
    for (int m=0;m<4;++m)
      #pragma unroll
      for (int n=0;n<4;++n)
        acc[m][n] = __builtin_amdgcn_mfma_f32_16x16x32_bf16(af[m], bf[n], acc[m][n], 0,0,0);
  }

  #pragma unroll
  for (int m=0;m<4;++m){
    #pragma unroll
    for (int r=0;r<4;++r){
      int row = m0 + wr*64 + m*16 + (l>>4)*4 + r;
      if (row >= NN) continue;
      #pragma unroll
      for (int n=0;n<4;++n){
        int col = n0 + wc*64 + n*16 + (l&15);
        float v = acc[m][n][r];
        size_t idx = (size_t)row*DD + col;
        if (MODE==0){
          float hv = v + bias[col];
          o32[idx] = hv;
          o16[idx] = f2b(hv);
        } else if (MODE==1){
          o16[idx] = f2b(v);
        } else {
          o32[idx] = v + bias[col];
        }
      }
    }
  }
}

// ---------------- degree / CSR build ----------------
__global__ void k_count(const int* __restrict__ dst, int* __restrict__ cnt){
  int e = blockIdx.x*256 + threadIdx.x;
  if (e < EE) atomicAdd(&cnt[dst[e]], 1);
}
__global__ void k_dinv(const int* __restrict__ cnt, float* __restrict__ dinv){
  int i = blockIdx.x*256 + threadIdx.x;
  if (i < MP) dinv[i] = (i < NN) ? rsqrtf((float)cnt[i] + 1.0f) : 0.f;
}
// per-block sums of cnt (256 per block)
__global__ void k_bsum(const int* __restrict__ cnt, int* __restrict__ bsum){
  int i = blockIdx.x*256 + threadIdx.x;
  int v = (i < NN) ? cnt[i] : 0;
  #pragma unroll
  for (int o=1;o<64;o<<=1) v += __shfl_xor(v, o);
  __shared__ int ws_[4];
  if ((threadIdx.x&63)==0) ws_[threadIdx.x>>6] = v;
  __syncthreads();
  if (threadIdx.x==0) bsum[blockIdx.x] = ws_[0]+ws_[1]+ws_[2]+ws_[3];
}
__global__ void k_btop(const int* __restrict__ bsum, int* __restrict__ boff){
  if (threadIdx.x==0){
    int run = 0;
    for (int b=0;b<SCB;++b){ boff[b] = run; run += bsum[b]; }
  }
}
__global__ void k_rowptr(const int* __restrict__ cnt, const int* __restrict__ boff,
                         int* __restrict__ rowptr, int* __restrict__ cursor){
  __shared__ int sh[256];
  int i = blockIdx.x*256 + threadIdx.x;
  int v = (i < NN) ? cnt[i] : 0;
  sh[threadIdx.x] = v; __syncthreads();
  #pragma unroll
  for (int o=1;o<256;o<<=1){
    int add = 0;
    if (threadIdx.x >= o) add = sh[threadIdx.x - o];
    __syncthreads();
    sh[threadIdx.x] += add;
    __syncthreads();
  }
  int excl = sh[threadIdx.x] - v + boff[blockIdx.x];
  if (i <= NN) rowptr[i] = excl;
  if (i < NN)  cursor[i] = excl;
}
__global__ void k_fill(const int* __restrict__ src, const int* __restrict__ dst,
                       const float* __restrict__ dinv, int* __restrict__ cursor,
                       int* __restrict__ ss, float* __restrict__ we){
  int e = blockIdx.x*256 + threadIdx.x;
  if (e < EE){
    int s = src[e], d = dst[e];
    int pos = atomicAdd(&cursor[d], 1);
    ss[pos] = s;
    we[pos] = dinv[s]*dinv[d];
  }
}
__global__ void k_x16(const float* __restrict__ x, unsigned short* __restrict__ x16){
  int idx = blockIdx.x*256 + threadIdx.x;
  if (idx < MP*KIN){
    int row = idx / KIN, k = idx - row*KIN;
    float v = (row < NN && k < 78) ? x[(size_t)row*78 + k] : 0.f;
    x16[idx] = f2b(v);
  }
}
// src [K x 768] fp32 -> dst [768 x ldk] bf16 (transposed, K-padded with zeros)
__global__ void k_tr(const float* __restrict__ src, unsigned short* __restrict__ dst, int K, int ldk){
  int idx = blockIdx.x*256 + threadIdx.x;
  if (idx < DD*ldk){
    int n = idx / ldk, k = idx - n*ldk;
    dst[idx] = (k < K) ? f2b(src[(size_t)k*DD + n]) : (unsigned short)0;
  }
}

// ---------------- CSR gather: agg = bias + dinv^2*xw[d] + sum en*xw[src]; fused BN stats ----------------
__global__ __launch_bounds__(256)
void k_gather(const int* __restrict__ rowptr, const int* __restrict__ ss,
              const float* __restrict__ we, const unsigned short* __restrict__ xw,
              const float* __restrict__ dinv, const float* __restrict__ bias,
              float* __restrict__ agg, float* __restrict__ stats){
  const int t = threadIdx.x;
  const float b0 = bias[t], b1 = bias[t+256], b2 = bias[t+512];
  float s0=0,s1=0,s2=0,q0=0,q1=0,q2=0;
  for (int d = blockIdx.x; d < NN; d += gridDim.x){
    int beg = rowptr[d], end = rowptr[d+1];
    float dv = dinv[d], sn = dv*dv;
    const unsigned short* xr = xw + (size_t)d*DD;
    float a0 = fmaf(sn, b2f(xr[t    ]), b0);
    float a1 = fmaf(sn, b2f(xr[t+256]), b1);
    float a2 = fmaf(sn, b2f(xr[t+512]), b2);
    for (int e=beg; e<end; ++e){
      int s = ss[e]; float wt = we[e];
      const unsigned short* xs = xw + (size_t)s*DD;
      a0 = fmaf(wt, b2f(xs[t    ]), a0);
      a1 = fmaf(wt, b2f(xs[t+256]), a1);
      a2 = fmaf(wt, b2f(xs[t+512]), a2);
    }
    float* ar = agg + (size_t)d*DD;
    ar[t] = a0; ar[t+256] = a1; ar[t+512] = a2;
    s0 += a0; q0 += a0*a0;
    s1 += a1; q1 += a1*a1;
    s2 += a2; q2 += a2*a2;
  }
  atomicAdd(&stats[t],        s0); atomicAdd(&stats[t+256],     s1); atomicAdd(&stats[t+512],     s2);
  atomicAdd(&stats[DD+t],     q0); atomicAdd(&stats[DD+t+256],  q1); atomicAdd(&stats[DD+t+512],  q2);
}

__global__ void k_final(const float* __restrict__ stats, const float* __restrict__ g,
                        const float* __restrict__ b, float* __restrict__ sc, float* __restrict__ sh){
  int t = threadIdx.x;
  #pragma unroll
  for (int j=0;j<3;++j){
    int d = t + j*256;
    float mu  = stats[d]      * (1.0f/NN);
    float msq = stats[DD+d]   * (1.0f/NN);
    float var = msq - mu*mu;
    float rstd = rsqrtf(var + 1e-5f);
    float scale = rstd * g[d];
    sc[d] = scale;
    sh[d] = b[d] - mu*scale;
  }
}
__global__ void k_apply(const float* __restrict__ agg, const float* __restrict__ sc,
                        const float* __restrict__ sh, float* __restrict__ h32,
                        unsigned short* __restrict__ h16){
  const int total = NN*DD/4;
  for (int i = blockIdx.x*blockDim.x + threadIdx.x; i < total; i += gridDim.x*blockDim.x){
    size_t base = (size_t)i*4;
    int col = (int)(base % DD);
    float4 a  = *(const float4*)(agg + base);
    float4 h  = *(const float4*)(h32 + base);
    float4 s  = *(const float4*)(sc + col);
    float4 t4 = *(const float4*)(sh + col);
    float o0 = h.x + fmaxf(fmaf(a.x, s.x, t4.x), 0.f);
    float o1 = h.y + fmaxf(fmaf(a.y, s.y, t4.y), 0.f);
    float o2 = h.z + fmaxf(fmaf(a.z, s.z, t4.z), 0.f);
    float o3 = h.w + fmaxf(fmaf(a.w, s.w, t4.w), 0.f);
    float4 ho = {o0,o1,o2,o3};
    *(float4*)(h32 + base) = ho;
    ushort4 hb = {f2b(o0), f2b(o1), f2b(o2), f2b(o3)};
    *(ushort4*)(h16 + base) = hb;
  }
}

extern "C" void kernel_launch(void* const* d_in, const int* in_sizes, int n_in,
                              void* d_out, int out_size, void* d_ws, size_t ws_size,
                              hipStream_t stream){
  (void)in_sizes; (void)n_in; (void)out_size; (void)ws_size;
  const float* x      = (const float*)d_in[0];
  const int*   ei     = (const int*)  d_in[1];
  const float* in_w   = (const float*)d_in[2];
  const float* in_b   = (const float*)d_in[3];
  const float* conv_w = (const float*)d_in[4];
  const float* conv_b = (const float*)d_in[5];
  const float* bn_g   = (const float*)d_in[6];
  const float* bn_b   = (const float*)d_in[7];
  const float* out_w  = (const float*)d_in[8];
  const float* out_b  = (const float*)d_in[9];
  float* out = (float*)d_out;
  const int* srcI = ei;
  const int* dstI = ei + EE;

  char* ws = (char*)d_ws; size_t off = 0;
  auto alloc = [&](size_t b)->void*{ void* p = ws + off; off += (b + 255) & ~(size_t)255; return p; };
  unsigned short* h16  = (unsigned short*)alloc((size_t)MP*DD*2);
  unsigned short* xw16 = (unsigned short*)alloc((size_t)MP*DD*2);
  float*          agg  = (float*)alloc((size_t)NN*DD*4);
  unsigned short* x16  = (unsigned short*)alloc((size_t)MP*KIN*2);
  unsigned short* wT   = (unsigned short*)alloc((size_t)(DD*KIN + 6*DD*DD)*2);
  float* dinv   = (float*)alloc((size_t)MP*4);
  int*   cnt    = (int*)  alloc((size_t)MP*4);
  int*   rowptr = (int*)  alloc((size_t)(NN+1)*4);
  int*   cursor = (int*)  alloc((size_t)NN*4);
  int*   ssE    = (int*)  alloc((size_t)EE*4);
  float* weE    = (float*)alloc((size_t)EE*4);
  int*   bsum   = (int*)  alloc((size_t)SCB*4);
  int*   boff   = (int*)  alloc((size_t)SCB*4);
  float* stats  = (float*)alloc((size_t)4*DD*4);
  float* h32 = out;  // d_out doubles as fp32 h (rows < NN only; overwritten by out proj at the end)

  unsigned short* wTin = wT;
  unsigned short* wTc  = wT + DD*KIN;
  unsigned short* wTo  = wTc + 5*DD*DD;

  hipMemsetAsync(cnt, 0, (size_t)MP*4, stream);
  hipMemsetAsync(h16 + (size_t)NN*DD, 0, (size_t)(MP-NN)*DD*2, stream);  // zero pad rows of h16
  k_count<<<(EE+255)/256,256,0,stream>>>(dstI, cnt);
  k_dinv <<<(MP+255)/256,256,0,stream>>>(cnt, dinv);
  k_bsum <<<SCB,256,0,stream>>>(cnt, bsum);
  k_btop <<<1,64,0,stream>>>(bsum, boff);
  k_rowptr<<<SCB,256,0,stream>>>(cnt, boff, rowptr, cursor);
  k_fill <<<(EE+255)/256,256,0,stream>>>(srcI, dstI, dinv, cursor, ssE, weE);
  k_x16  <<<(MP*KIN+255)/256,256,0,stream>>>(x, x16);
  k_tr   <<<(DD*KIN+255)/256,256,0,stream>>>(in_w, wTin, 78, KIN);
  for (int l = 0; l < 5; ++l)
    k_tr <<<(DD*DD+255)/256,256,0,stream>>>(conv_w + (size_t)l*DD*DD, wTc + (size_t)l*DD*DD, DD, DD);
  k_tr   <<<(DD*DD+255)/256,256,0,stream>>>(out_w, wTo, DD, DD);

  dim3 gg(MP/128, DD/128);
  gemm_k<0><<<gg,256,0,stream>>>(x16, wTin, KIN, in_b, h32, h16);

  for (int l = 0; l < 5; ++l){
    gemm_k<1><<<gg,256,0,stream>>>(h16, wTc + (size_t)l*DD*DD, DD, nullptr, nullptr, xw16);
    hipMemsetAsync(stats, 0, (size_t)2*DD*4, stream);
    k_gather<<<2048,256,0,stream>>>(rowptr, ssE, weE, xw16, dinv, conv_b + l*DD, agg, stats);
    k_final<<<1,256,0,stream>>>(stats, bn_g + l*DD, bn_b + l*DD, stats+2*DD, stats+3*DD);
    k_apply<<<2048,256,0,stream>>>(agg, stats+2*DD, stats+3*DD, h32, h16);
  }

  gemm_k<2><<<gg,256,0,stream>>>(h16, wTo, DD, out_b, out, nullptr);
}

// Round 3
// 1707.964 us; speedup vs baseline: 1.7456x; 1.0826x over previous
//
#include <hip/hip_runtime.h>
#include <hip/hip_bf16.h>
#include <stdint.h>

#define NN 50000
#define EE 100000
#define DD 768
#define MP 50048   // 391 * 128
#define KIN 96     // 78 padded to 96
#define SCB 196    // ceil(50000/256) scan blocks

typedef __attribute__((ext_vector_type(8))) short v8s;
typedef __attribute__((ext_vector_type(4))) float v4f;

__device__ inline float b2f(unsigned short u){ return __uint_as_float(((unsigned)u)<<16); }
__device__ inline unsigned short f2b(float f){
  unsigned u = __float_as_uint(f);
  u += 0x7fffu + ((u>>16)&1u);
  return (unsigned short)(u>>16);
}

__device__ __forceinline__ void gload16(const unsigned short* g, unsigned short* l){
  __builtin_amdgcn_global_load_lds(
      (const __attribute__((address_space(1))) unsigned int*)(g),
      (__attribute__((address_space(3))) unsigned int*)(l),
      16, 0, 0);
}

// ---------------- GEMM: C[M x 768] = A[M x K](bf16) * Bt[768 x K]^T (bf16) ----------------
// Grid: flattened 2346 blocks, bijective XCD-chunk swizzle, col-block fastest.
// MODE 0: input proj  -> h32 = acc + bias; h16 = bf16(h32)
// MODE 1: conv        -> xw16 = bf16(acc)          (bias/self-loop applied in gather)
// MODE 2: out proj    -> o32 = acc + bias
template<int MODE>
__global__ __launch_bounds__(256)
void gemm_k(const unsigned short* __restrict__ A,
            const unsigned short* __restrict__ Bt,
            int K,
            const float* __restrict__ bias,
            float* __restrict__ o32,
            unsigned short* __restrict__ o16)
{
  __shared__ __align__(16) unsigned short As[128*32];
  __shared__ __align__(16) unsigned short Bs[128*32];
  // bijective XCD swizzle (m204): consecutive logical ids land on one XCD chunk
  const int nwg = gridDim.x;
  const int q = nwg >> 3, r = nwg & 7;
  const int xcd = blockIdx.x & 7, ii = blockIdx.x >> 3;
  const int L = (xcd < r ? xcd*(q+1) : r*(q+1) + (xcd-r)*q) + ii;
  const int rowb = L / 6, colb = L - rowb*6;      // col-fastest: 6 col-blocks share A-tile
  const int m0 = rowb*128, n0 = colb*128;

  const int t = threadIdx.x, l = t&63, w = t>>6;
  const int wr = w>>1, wc = w&1;
  v4f acc[4][4];
  #pragma unroll
  for (int i=0;i<4;++i)
    #pragma unroll
    for (int j=0;j<4;++j){ v4f z = {0.f,0.f,0.f,0.f}; acc[i][j]=z; }

  const int nkt = K/32;
  for (int kt=0; kt<nkt; ++kt){
    __syncthreads();
    // async stage: linear LDS dest, pre-swizzled global source (involution kept with reads)
    #pragma unroll
    for (int j=0;j<2;++j){
      int br  = w*32 + j*16;                 // wave-uniform LDS base row
      int row = br + (l>>2);
      int ch  = (l&3) ^ ((row>>1)&3);        // source pre-swizzle
      gload16(A  + (size_t)(m0+row)*K + kt*32 + ch*8, As + br*32);
      gload16(Bt + (size_t)(n0+row)*K + kt*32 + ch*8, Bs + br*32);
    }
    __syncthreads();                          // compiler drains vmcnt before barrier
    v8s af[4], bf[4];
    #pragma unroll
    for (int m=0;m<4;++m){
      int row = wr*64 + m*16 + (l&15);
      int ch = (l>>4) ^ ((row>>1)&3);
      af[m] = *(const v8s*)(As + row*32 + ch*8);
    }
    #pragma unroll
    for (int n=0;n<4;++n){
      int row = wc*64 + n*16 + (l&15);
      int ch = (l>>4) ^ ((row>>1)&3);
      bf[n] = *(const v8s*)(Bs + row*32 + ch*8);
    }
    #pragma unroll
    for (int m=0;m<4;++m)
      #pragma unroll
      for (int n=0;n<4;++n)
        acc[m][n] = __builtin_amdgcn_mfma_f32_16x16x32_bf16(af[m], bf[n], acc[m][n], 0,0,0);
  }

  #pragma unroll
  for (int m=0;m<4;++m){
    #pragma unroll
    for (int rr=0;rr<4;++rr){
      int row = m0 + wr*64 + m*16 + (l>>4)*4 + rr;
      if (row >= NN) continue;
      #pragma unroll
      for (int n=0;n<4;++n){
        int col = n0 + wc*64 + n*16 + (l&15);
        float v = acc[m][n][rr];
        size_t idx = (size_t)row*DD + col;
        if (MODE==0){
          float hv = v + bias[col];
          o32[idx] = hv;
          o16[idx] = f2b(hv);
        } else if (MODE==1){
          o16[idx] = f2b(v);
        } else {
          o32[idx] = v + bias[col];
        }
      }
    }
  }
}

// ---------------- degree / CSR build ----------------
__global__ void k_count(const int* __restrict__ dst, int* __restrict__ cnt){
  int e = blockIdx.x*256 + threadIdx.x;
  if (e < EE) atomicAdd(&cnt[dst[e]], 1);
}
__global__ void k_dinv(const int* __restrict__ cnt, float* __restrict__ dinv){
  int i = blockIdx.x*256 + threadIdx.x;
  if (i < MP) dinv[i] = (i < NN) ? rsqrtf((float)cnt[i] + 1.0f) : 0.f;
}
__global__ void k_bsum(const int* __restrict__ cnt, int* __restrict__ bsum){
  int i = blockIdx.x*256 + threadIdx.x;
  int v = (i < NN) ? cnt[i] : 0;
  #pragma unroll
  for (int o=1;o<64;o<<=1) v += __shfl_xor(v, o);
  __shared__ int ws_[4];
  if ((threadIdx.x&63)==0) ws_[threadIdx.x>>6] = v;
  __syncthreads();
  if (threadIdx.x==0) bsum[blockIdx.x] = ws_[0]+ws_[1]+ws_[2]+ws_[3];
}
__global__ void k_btop(const int* __restrict__ bsum, int* __restrict__ boff){
  if (threadIdx.x==0){
    int run = 0;
    for (int b=0;b<SCB;++b){ boff[b] = run; run += bsum[b]; }
  }
}
__global__ void k_rowptr(const int* __restrict__ cnt, const int* __restrict__ boff,
                         int* __restrict__ rowptr, int* __restrict__ cursor){
  __shared__ int sh[256];
  int i = blockIdx.x*256 + threadIdx.x;
  int v = (i < NN) ? cnt[i] : 0;
  sh[threadIdx.x] = v; __syncthreads();
  #pragma unroll
  for (int o=1;o<256;o<<=1){
    int add = 0;
    if (threadIdx.x >= o) add = sh[threadIdx.x - o];
    __syncthreads();
    sh[threadIdx.x] += add;
    __syncthreads();
  }
  int excl = sh[threadIdx.x] - v + boff[blockIdx.x];
  if (i <= NN) rowptr[i] = excl;
  if (i < NN)  cursor[i] = excl;
}
__global__ void k_fill(const int* __restrict__ src, const int* __restrict__ dst,
                       const float* __restrict__ dinv, int* __restrict__ cursor,
                       int* __restrict__ ss, float* __restrict__ we){
  int e = blockIdx.x*256 + threadIdx.x;
  if (e < EE){
    int s = src[e], d = dst[e];
    int pos = atomicAdd(&cursor[d], 1);
    ss[pos] = s;
    we[pos] = dinv[s]*dinv[d];
  }
}
__global__ void k_x16(const float* __restrict__ x, unsigned short* __restrict__ x16){
  int idx = blockIdx.x*256 + threadIdx.x;
  if (idx < MP*KIN){
    int row = idx / KIN, k = idx - row*KIN;
    float v = (row < NN && k < 78) ? x[(size_t)row*78 + k] : 0.f;
    x16[idx] = f2b(v);
  }
}
__global__ void k_tr(const float* __restrict__ src, unsigned short* __restrict__ dst, int K, int ldk){
  int idx = blockIdx.x*256 + threadIdx.x;
  if (idx < DD*ldk){
    int n = idx / ldk, k = idx - n*ldk;
    dst[idx] = (k < K) ? f2b(src[(size_t)k*DD + n]) : (unsigned short)0;
  }
}

// ---------------- CSR gather: agg16 = bf16(bias + dinv^2*xw[d] + sum en*xw[src]); fused BN stats ----------------
__global__ __launch_bounds__(256)
void k_gather(const int* __restrict__ rowptr, const int* __restrict__ ss,
              const float* __restrict__ we, const unsigned short* __restrict__ xw,
              const float* __restrict__ dinv, const float* __restrict__ bias,
              unsigned short* __restrict__ agg16, float* __restrict__ stats){
  const int t = threadIdx.x;
  const float b0 = bias[t], b1 = bias[t+256], b2 = bias[t+512];
  float s0=0,s1=0,s2=0,q0=0,q1=0,q2=0;
  for (int d = blockIdx.x; d < NN; d += gridDim.x){
    int beg = rowptr[d], end = rowptr[d+1];
    float dv = dinv[d], sn = dv*dv;
    const unsigned short* xr = xw + (size_t)d*DD;
    float a0 = fmaf(sn, b2f(xr[t    ]), b0);
    float a1 = fmaf(sn, b2f(xr[t+256]), b1);
    float a2 = fmaf(sn, b2f(xr[t+512]), b2);
    for (int e=beg; e<end; ++e){
      int s = ss[e]; float wt = we[e];
      const unsigned short* xs = xw + (size_t)s*DD;
      a0 = fmaf(wt, b2f(xs[t    ]), a0);
      a1 = fmaf(wt, b2f(xs[t+256]), a1);
      a2 = fmaf(wt, b2f(xs[t+512]), a2);
    }
    unsigned short* ar = agg16 + (size_t)d*DD;
    ar[t] = f2b(a0); ar[t+256] = f2b(a1); ar[t+512] = f2b(a2);
    s0 += a0; q0 += a0*a0;
    s1 += a1; q1 += a1*a1;
    s2 += a2; q2 += a2*a2;
  }
  atomicAdd(&stats[t],        s0); atomicAdd(&stats[t+256],     s1); atomicAdd(&stats[t+512],     s2);
  atomicAdd(&stats[DD+t],     q0); atomicAdd(&stats[DD+t+256],  q1); atomicAdd(&stats[DD+t+512],  q2);
}

__global__ void k_final(const float* __restrict__ stats, const float* __restrict__ g,
                        const float* __restrict__ b, float* __restrict__ sc, float* __restrict__ sh){
  int t = threadIdx.x;
  #pragma unroll
  for (int j=0;j<3;++j){
    int d = t + j*256;
    float mu  = stats[d]      * (1.0f/NN);
    float msq = stats[DD+d]   * (1.0f/NN);
    float var = msq - mu*mu;
    float rstd = rsqrtf(var + 1e-5f);
    float scale = rstd * g[d];
    sc[d] = scale;
    sh[d] = b[d] - mu*scale;
  }
}
__global__ void k_apply(const unsigned short* __restrict__ agg16, const float* __restrict__ sc,
                        const float* __restrict__ sh, float* __restrict__ h32,
                        unsigned short* __restrict__ h16){
  const int total = NN*DD/8;
  for (int i = blockIdx.x*blockDim.x + threadIdx.x; i < total; i += gridDim.x*blockDim.x){
    size_t base = (size_t)i*8;
    int col = (int)(base % DD);
    uint4 av = *(const uint4*)(agg16 + base);
    float4 h0 = *(const float4*)(h32 + base);
    float4 h1 = *(const float4*)(h32 + base + 4);
    float4 s0 = *(const float4*)(sc + col);
    float4 s1 = *(const float4*)(sc + col + 4);
    float4 t0 = *(const float4*)(sh + col);
    float4 t1 = *(const float4*)(sh + col + 4);
    float a0 = b2f((unsigned short)(av.x & 0xffff)), a1 = b2f((unsigned short)(av.x >> 16));
    float a2 = b2f((unsigned short)(av.y & 0xffff)), a3 = b2f((unsigned short)(av.y >> 16));
    float a4 = b2f((unsigned short)(av.z & 0xffff)), a5 = b2f((unsigned short)(av.z >> 16));
    float a6 = b2f((unsigned short)(av.w & 0xffff)), a7 = b2f((unsigned short)(av.w >> 16));
    float o0 = h0.x + fmaxf(fmaf(a0, s0.x, t0.x), 0.f);
    float o1 = h0.y + fmaxf(fmaf(a1, s0.y, t0.y), 0.f);
    float o2 = h0.z + fmaxf(fmaf(a2, s0.z, t0.z), 0.f);
    float o3 = h0.w + fmaxf(fmaf(a3, s0.w, t0.w), 0.f);
    float o4 = h1.x + fmaxf(fmaf(a4, s1.x, t1.x), 0.f);
    float o5 = h1.y + fmaxf(fmaf(a5, s1.y, t1.y), 0.f);
    float o6 = h1.z + fmaxf(fmaf(a6, s1.z, t1.z), 0.f);
    float o7 = h1.w + fmaxf(fmaf(a7, s1.w, t1.w), 0.f);
    float4 w0 = {o0,o1,o2,o3}, w1 = {o4,o5,o6,o7};
    *(float4*)(h32 + base)     = w0;
    *(float4*)(h32 + base + 4) = w1;
    uint4 hb;
    hb.x = (unsigned)f2b(o0) | ((unsigned)f2b(o1)<<16);
    hb.y = (unsigned)f2b(o2) | ((unsigned)f2b(o3)<<16);
    hb.z = (unsigned)f2b(o4) | ((unsigned)f2b(o5)<<16);
    hb.w = (unsigned)f2b(o6) | ((unsigned)f2b(o7)<<16);
    *(uint4*)(h16 + base) = hb;
  }
}

extern "C" void kernel_launch(void* const* d_in, const int* in_sizes, int n_in,
                              void* d_out, int out_size, void* d_ws, size_t ws_size,
                              hipStream_t stream){
  (void)in_sizes; (void)n_in; (void)out_size; (void)ws_size;
  const float* x      = (const float*)d_in[0];
  const int*   ei     = (const int*)  d_in[1];
  const float* in_w   = (const float*)d_in[2];
  const float* in_b   = (const float*)d_in[3];
  const float* conv_w = (const float*)d_in[4];
  const float* conv_b = (const float*)d_in[5];
  const float* bn_g   = (const float*)d_in[6];
  const float* bn_b   = (const float*)d_in[7];
  const float* out_w  = (const float*)d_in[8];
  const float* out_b  = (const float*)d_in[9];
  float* out = (float*)d_out;
  const int* srcI = ei;
  const int* dstI = ei + EE;

  char* ws = (char*)d_ws; size_t off = 0;
  auto alloc = [&](size_t b)->void*{ void* p = ws + off; off += (b + 255) & ~(size_t)255; return p; };
  unsigned short* h16  = (unsigned short*)alloc((size_t)MP*DD*2);
  unsigned short* xw16 = (unsigned short*)alloc((size_t)MP*DD*2);
  unsigned short* agg16= (unsigned short*)alloc((size_t)NN*DD*2);
  unsigned short* x16  = (unsigned short*)alloc((size_t)MP*KIN*2);
  unsigned short* wT   = (unsigned short*)alloc((size_t)(DD*KIN + 6*DD*DD)*2);
  float* dinv   = (float*)alloc((size_t)MP*4);
  int*   cnt    = (int*)  alloc((size_t)MP*4);
  int*   rowptr = (int*)  alloc((size_t)(NN+1)*4);
  int*   cursor = (int*)  alloc((size_t)NN*4);
  int*   ssE    = (int*)  alloc((size_t)EE*4);
  float* weE    = (float*)alloc((size_t)EE*4);
  int*   bsum   = (int*)  alloc((size_t)SCB*4);
  int*   boff   = (int*)  alloc((size_t)SCB*4);
  float* stats  = (float*)alloc((size_t)4*DD*4);
  float* h32 = out;  // d_out doubles as fp32 h (rows < NN only; overwritten by out proj at the end)

  unsigned short* wTin = wT;
  unsigned short* wTc  = wT + DD*KIN;
  unsigned short* wTo  = wTc + 5*DD*DD;

  hipMemsetAsync(cnt, 0, (size_t)MP*4, stream);
  hipMemsetAsync(h16 + (size_t)NN*DD, 0, (size_t)(MP-NN)*DD*2, stream);  // zero pad rows of h16
  k_count<<<(EE+255)/256,256,0,stream>>>(dstI, cnt);
  k_dinv <<<(MP+255)/256,256,0,stream>>>(cnt, dinv);
  k_bsum <<<SCB,256,0,stream>>>(cnt, bsum);
  k_btop <<<1,64,0,stream>>>(bsum, boff);
  k_rowptr<<<SCB,256,0,stream>>>(cnt, boff, rowptr, cursor);
  k_fill <<<(EE+255)/256,256,0,stream>>>(srcI, dstI, dinv, cursor, ssE, weE);
  k_x16  <<<(MP*KIN+255)/256,256,0,stream>>>(x, x16);
  k_tr   <<<(DD*KIN+255)/256,256,0,stream>>>(in_w, wTin, 78, KIN);
  for (int l = 0; l < 5; ++l)
    k_tr <<<(DD*DD+255)/256,256,0,stream>>>(conv_w + (size_t)l*DD*DD, wTc + (size_t)l*DD*DD, DD, DD);
  k_tr   <<<(DD*DD+255)/256,256,0,stream>>>(out_w, wTo, DD, DD);

  const int NWG = (MP/128)*(DD/128);   // 2346
  gemm_k<0><<<NWG,256,0,stream>>>(x16, wTin, KIN, in_b, h32, h16);

  for (int l = 0; l < 5; ++l){
    gemm_k<1><<<NWG,256,0,stream>>>(h16, wTc + (size_t)l*DD*DD, DD, nullptr, nullptr, xw16);
    hipMemsetAsync(stats, 0, (size_t)2*DD*4, stream);
    k_gather<<<2048,256,0,stream>>>(rowptr, ssE, weE, xw16, dinv, conv_b + l*DD, agg16, stats);
    k_final<<<1,256,0,stream>>>(stats, bn_g + l*DD, bn_b + l*DD, stats+2*DD, stats+3*DD);
    k_apply<<<2048,256,0,stream>>>(agg16, stats+2*DD, stats+3*DD, h32, h16);
  }

  gemm_k<2><<<NWG,256,0,stream>>>(h16, wTo, DD, out_b, out, nullptr);
}

// Round 4
// 1320.257 us; speedup vs baseline: 2.2583x; 1.2937x over previous
//
#include <hip/hip_runtime.h>
#include <hip/hip_bf16.h>
#include <stdint.h>

#define NN 50000
#define EE 100000
#define DD 768
#define MP 50048   // 391 * 128
#define KIN 96     // 78 padded to 96
#define SCB 196    // ceil(50000/256) scan blocks

typedef _Float16 half_t;
typedef __attribute__((ext_vector_type(8))) _Float16 v8h;
typedef __attribute__((ext_vector_type(4))) float v4f;

__device__ __forceinline__ void gload16(const half_t* g, half_t* l){
  __builtin_amdgcn_global_load_lds(
      (const __attribute__((address_space(1))) unsigned int*)(g),
      (__attribute__((address_space(3))) unsigned int*)(l),
      16, 0, 0);
}

// ---------------- GEMM: C[M x 768] = A[M x K](f16) * Bt[768 x K]^T (f16) ----------------
// Grid: flattened, bijective XCD-chunk swizzle, col-block fastest (6 col-blocks share A-tile).
// MODE 0: input proj  -> h16 = f16(acc + bias)     (LDS-transpose epilogue, coalesced)
// MODE 1: conv        -> xw16 = f16(acc)           (LDS-transpose epilogue, coalesced)
// MODE 2: out proj    -> o32 = acc + bias          (fp32 direct stores)
template<int MODE>
__global__ __launch_bounds__(256)
void gemm_k(const half_t* __restrict__ A,
            const half_t* __restrict__ Bt,
            int K,
            const float* __restrict__ bias,
            float* __restrict__ o32,
            half_t* __restrict__ o16)
{
  __shared__ __align__(16) half_t smem[128*128];   // 32KB: K-loop uses first 16KB (As|Bs); epilogue uses all
  half_t* As = smem;                // 128*32
  half_t* Bs = smem + 128*32;       // 128*32
  // bijective XCD swizzle (m204)
  const int nwg = gridDim.x;
  const int q = nwg >> 3, r = nwg & 7;
  const int xcd = blockIdx.x & 7, ii = blockIdx.x >> 3;
  const int L = (xcd < r ? xcd*(q+1) : r*(q+1) + (xcd-r)*q) + ii;
  const int rowb = L / 6, colb = L - rowb*6;
  const int m0 = rowb*128, n0 = colb*128;

  const int t = threadIdx.x, l = t&63, w = t>>6;
  const int wr = w>>1, wc = w&1;
  v4f acc[4][4];
  #pragma unroll
  for (int i=0;i<4;++i)
    #pragma unroll
    for (int j=0;j<4;++j){ v4f z = {0.f,0.f,0.f,0.f}; acc[i][j]=z; }

  const int nkt = K/32;
  for (int kt=0; kt<nkt; ++kt){
    __syncthreads();
    // async stage: linear LDS dest, pre-swizzled per-lane global source
    #pragma unroll
    for (int j=0;j<2;++j){
      int br  = w*32 + j*16;                 // wave-uniform LDS base row
      int row = br + (l>>2);
      int ch  = (l&3) ^ ((row>>1)&3);        // source pre-swizzle (involution kept with reads)
      gload16(A  + (size_t)(m0+row)*K + kt*32 + ch*8, As + br*32);
      gload16(Bt + (size_t)(n0+row)*K + kt*32 + ch*8, Bs + br*32);
    }
    __syncthreads();
    v8h af[4], bf[4];
    #pragma unroll
    for (int m=0;m<4;++m){
      int row = wr*64 + m*16 + (l&15);
      int ch = (l>>4) ^ ((row>>1)&3);
      af[m] = *(const v8h*)(As + row*32 + ch*8);
    }
    #pragma unroll
    for (int n=0;n<4;++n){
      int row = wc*64 + n*16 + (l&15);
      int ch = (l>>4) ^ ((row>>1)&3);
      bf[n] = *(const v8h*)(Bs + row*32 + ch*8);
    }
    #pragma unroll
    for (int m=0;m<4;++m)
      #pragma unroll
      for (int n=0;n<4;++n)
        acc[m][n] = __builtin_amdgcn_mfma_f32_16x16x32_f16(af[m], bf[n], acc[m][n], 0,0,0);
  }

  if (MODE==2){
    #pragma unroll
    for (int m=0;m<4;++m){
      #pragma unroll
      for (int rr=0;rr<4;++rr){
        int row = m0 + wr*64 + m*16 + (l>>4)*4 + rr;
        if (row >= NN) continue;
        #pragma unroll
        for (int n=0;n<4;++n){
          int col = n0 + wc*64 + n*16 + (l&15);
          o32[(size_t)row*DD + col] = acc[m][n][rr] + bias[col];
        }
      }
    }
  } else {
    // LDS-transpose epilogue: acc -> swizzled LDS halfs -> coalesced 16B stores
    __syncthreads();   // all waves done reading As/Bs
    #pragma unroll
    for (int m=0;m<4;++m){
      #pragma unroll
      for (int rr=0;rr<4;++rr){
        int row = wr*64 + m*16 + (l>>4)*4 + rr;
        #pragma unroll
        for (int n=0;n<4;++n){
          int colL = wc*64 + n*16 + (l&15);
          float v = acc[m][n][rr];
          if (MODE==0) v += bias[n0+colL];
          int col = colL ^ (((row>>2)&3)<<4);
          smem[row*128 + col] = (half_t)v;
        }
      }
    }
    __syncthreads();
    #pragma unroll
    for (int c=0;c<8;++c){
      int row = c*16 + (t>>4);
      int colBase = (t&15)*8;
      int col = colBase ^ (((row>>2)&3)<<4);
      v8h hv = *(const v8h*)(smem + row*128 + col);
      *(v8h*)(o16 + (size_t)(m0+row)*DD + n0 + colBase) = hv;   // pad rows (>=NN) harmless
    }
  }
}

// ---------------- degree / CSR build ----------------
__global__ void k_count(const int* __restrict__ dst, int* __restrict__ cnt){
  int e = blockIdx.x*256 + threadIdx.x;
  if (e < EE) atomicAdd(&cnt[dst[e]], 1);
}
__global__ void k_dinv(const int* __restrict__ cnt, float* __restrict__ dinv){
  int i = blockIdx.x*256 + threadIdx.x;
  if (i < MP) dinv[i] = (i < NN) ? rsqrtf((float)cnt[i] + 1.0f) : 0.f;
}
__global__ void k_bsum(const int* __restrict__ cnt, int* __restrict__ bsum){
  int i = blockIdx.x*256 + threadIdx.x;
  int v = (i < NN) ? cnt[i] : 0;
  #pragma unroll
  for (int o=1;o<64;o<<=1) v += __shfl_xor(v, o);
  __shared__ int ws_[4];
  if ((threadIdx.x&63)==0) ws_[threadIdx.x>>6] = v;
  __syncthreads();
  if (threadIdx.x==0) bsum[blockIdx.x] = ws_[0]+ws_[1]+ws_[2]+ws_[3];
}
__global__ void k_btop(const int* __restrict__ bsum, int* __restrict__ boff){
  if (threadIdx.x==0){
    int run = 0;
    for (int b=0;b<SCB;++b){ boff[b] = run; run += bsum[b]; }
  }
}
__global__ void k_rowptr(const int* __restrict__ cnt, const int* __restrict__ boff,
                         int* __restrict__ rowptr, int* __restrict__ cursor){
  __shared__ int sh[256];
  int i = blockIdx.x*256 + threadIdx.x;
  int v = (i < NN) ? cnt[i] : 0;
  sh[threadIdx.x] = v; __syncthreads();
  #pragma unroll
  for (int o=1;o<256;o<<=1){
    int add = 0;
    if (threadIdx.x >= o) add = sh[threadIdx.x - o];
    __syncthreads();
    sh[threadIdx.x] += add;
    __syncthreads();
  }
  int excl = sh[threadIdx.x] - v + boff[blockIdx.x];
  if (i <= NN) rowptr[i] = excl;
  if (i < NN)  cursor[i] = excl;
}
__global__ void k_fill(const int* __restrict__ src, const int* __restrict__ dst,
                       const float* __restrict__ dinv, int* __restrict__ cursor,
                       int* __restrict__ ss, float* __restrict__ we){
  int e = blockIdx.x*256 + threadIdx.x;
  if (e < EE){
    int s = src[e], d = dst[e];
    int pos = atomicAdd(&cursor[d], 1);
    ss[pos] = s;
    we[pos] = dinv[s]*dinv[d];
  }
}
__global__ void k_x16(const float* __restrict__ x, half_t* __restrict__ x16){
  int idx = blockIdx.x*256 + threadIdx.x;
  if (idx < MP*KIN){
    int row = idx / KIN, k = idx - row*KIN;
    float v = (row < NN && k < 78) ? x[(size_t)row*78 + k] : 0.f;
    x16[idx] = (half_t)v;
  }
}
__global__ void k_tr(const float* __restrict__ src, half_t* __restrict__ dst, int K, int ldk){
  int idx = blockIdx.x*256 + threadIdx.x;
  if (idx < DD*ldk){
    int n = idx / ldk, k = idx - n*ldk;
    dst[idx] = (k < K) ? (half_t)src[(size_t)k*DD + n] : (half_t)0.f;
  }
}

// ---------------- CSR gather: agg16 = f16(bias + dinv^2*xw[d] + sum en*xw[src]); fused BN stats ----------------
__global__ __launch_bounds__(256)
void k_gather(const int* __restrict__ rowptr, const int* __restrict__ ss,
              const float* __restrict__ we, const half_t* __restrict__ xw,
              const float* __restrict__ dinv, const float* __restrict__ bias,
              half_t* __restrict__ agg16, float* __restrict__ stats){
  const int t = threadIdx.x;
  const float b0 = bias[t], b1 = bias[t+256], b2 = bias[t+512];
  float s0=0,s1=0,s2=0,q0=0,q1=0,q2=0;
  for (int d = blockIdx.x; d < NN; d += gridDim.x){
    int beg = rowptr[d], end = rowptr[d+1];
    float dv = dinv[d], sn = dv*dv;
    const half_t* xr = xw + (size_t)d*DD;
    float a0 = fmaf(sn, (float)xr[t    ], b0);
    float a1 = fmaf(sn, (float)xr[t+256], b1);
    float a2 = fmaf(sn, (float)xr[t+512], b2);
    for (int e=beg; e<end; ++e){
      int s = ss[e]; float wt = we[e];
      const half_t* xs = xw + (size_t)s*DD;
      a0 = fmaf(wt, (float)xs[t    ], a0);
      a1 = fmaf(wt, (float)xs[t+256], a1);
      a2 = fmaf(wt, (float)xs[t+512], a2);
    }
    half_t* ar = agg16 + (size_t)d*DD;
    ar[t] = (half_t)a0; ar[t+256] = (half_t)a1; ar[t+512] = (half_t)a2;
    s0 += a0; q0 += a0*a0;
    s1 += a1; q1 += a1*a1;
    s2 += a2; q2 += a2*a2;
  }
  atomicAdd(&stats[t],        s0); atomicAdd(&stats[t+256],     s1); atomicAdd(&stats[t+512],     s2);
  atomicAdd(&stats[DD+t],     q0); atomicAdd(&stats[DD+t+256],  q1); atomicAdd(&stats[DD+t+512],  q2);
}

__global__ void k_final(const float* __restrict__ stats, const float* __restrict__ g,
                        const float* __restrict__ b, float* __restrict__ sc, float* __restrict__ sh){
  int t = threadIdx.x;
  #pragma unroll
  for (int j=0;j<3;++j){
    int d = t + j*256;
    float mu  = stats[d]      * (1.0f/NN);
    float msq = stats[DD+d]   * (1.0f/NN);
    float var = msq - mu*mu;
    float rstd = rsqrtf(var + 1e-5f);
    float scale = rstd * g[d];
    sc[d] = scale;
    sh[d] = b[d] - mu*scale;
  }
}
// h16 += relu(agg*sc + sh)   (fp16 residual state)
__global__ void k_apply(const half_t* __restrict__ agg16, const float* __restrict__ sc,
                        const float* __restrict__ sh, half_t* __restrict__ h16){
  const int total = NN*DD/8;
  for (int i = blockIdx.x*blockDim.x + threadIdx.x; i < total; i += gridDim.x*blockDim.x){
    size_t base = (size_t)i*8;
    int col = (int)(base % DD);
    v8h a = *(const v8h*)(agg16 + base);
    v8h h = *(const v8h*)(h16 + base);
    v8h o;
    #pragma unroll
    for (int j=0;j<8;++j){
      float v = fmaxf(fmaf((float)a[j], sc[col+j], sh[col+j]), 0.f);
      o[j] = (half_t)((float)h[j] + v);
    }
    *(v8h*)(h16 + base) = o;
  }
}

extern "C" void kernel_launch(void* const* d_in, const int* in_sizes, int n_in,
                              void* d_out, int out_size, void* d_ws, size_t ws_size,
                              hipStream_t stream){
  (void)in_sizes; (void)n_in; (void)out_size; (void)ws_size;
  const float* x      = (const float*)d_in[0];
  const int*   ei     = (const int*)  d_in[1];
  const float* in_w   = (const float*)d_in[2];
  const float* in_b   = (const float*)d_in[3];
  const float* conv_w = (const float*)d_in[4];
  const float* conv_b = (const float*)d_in[5];
  const float* bn_g   = (const float*)d_in[6];
  const float* bn_b   = (const float*)d_in[7];
  const float* out_w  = (const float*)d_in[8];
  const float* out_b  = (const float*)d_in[9];
  float* out = (float*)d_out;
  const int* srcI = ei;
  const int* dstI = ei + EE;

  char* ws = (char*)d_ws; size_t off = 0;
  auto alloc = [&](size_t b)->void*{ void* p = ws + off; off += (b + 255) & ~(size_t)255; return p; };
  half_t* h16  = (half_t*)alloc((size_t)MP*DD*2);
  half_t* xw16 = (half_t*)alloc((size_t)MP*DD*2);
  half_t* agg16= (half_t*)alloc((size_t)NN*DD*2);
  half_t* x16  = (half_t*)alloc((size_t)MP*KIN*2);
  half_t* wT   = (half_t*)alloc((size_t)(DD*KIN + 6*DD*DD)*2);
  float* dinv   = (float*)alloc((size_t)MP*4);
  int*   cnt    = (int*)  alloc((size_t)MP*4);
  int*   rowptr = (int*)  alloc((size_t)(NN+1)*4);
  int*   cursor = (int*)  alloc((size_t)NN*4);
  int*   ssE    = (int*)  alloc((size_t)EE*4);
  float* weE    = (float*)alloc((size_t)EE*4);
  int*   bsum   = (int*)  alloc((size_t)SCB*4);
  int*   boff   = (int*)  alloc((size_t)SCB*4);
  float* stats  = (float*)alloc((size_t)4*DD*4);

  half_t* wTin = wT;
  half_t* wTc  = wT + DD*KIN;
  half_t* wTo  = wTc + 5*DD*DD;

  hipMemsetAsync(cnt, 0, (size_t)MP*4, stream);
  k_count<<<(EE+255)/256,256,0,stream>>>(dstI, cnt);
  k_dinv <<<(MP+255)/256,256,0,stream>>>(cnt, dinv);
  k_bsum <<<SCB,256,0,stream>>>(cnt, bsum);
  k_btop <<<1,64,0,stream>>>(bsum, boff);
  k_rowptr<<<SCB,256,0,stream>>>(cnt, boff, rowptr, cursor);
  k_fill <<<(EE+255)/256,256,0,stream>>>(srcI, dstI, dinv, cursor, ssE, weE);
  k_x16  <<<(MP*KIN+255)/256,256,0,stream>>>(x, x16);
  k_tr   <<<(DD*KIN+255)/256,256,0,stream>>>(in_w, wTin, 78, KIN);
  for (int l = 0; l < 5; ++l)
    k_tr <<<(DD*DD+255)/256,256,0,stream>>>(conv_w + (size_t)l*DD*DD, wTc + (size_t)l*DD*DD, DD, DD);
  k_tr   <<<(DD*DD+255)/256,256,0,stream>>>(out_w, wTo, DD, DD);

  const int NWG = (MP/128)*(DD/128);   // 2346
  gemm_k<0><<<NWG,256,0,stream>>>(x16, wTin, KIN, in_b, nullptr, h16);

  for (int l = 0; l < 5; ++l){
    gemm_k<1><<<NWG,256,0,stream>>>(h16, wTc + (size_t)l*DD*DD, DD, nullptr, nullptr, xw16);
    hipMemsetAsync(stats, 0, (size_t)2*DD*4, stream);
    k_gather<<<2048,256,0,stream>>>(rowptr, ssE, weE, xw16, dinv, conv_b + l*DD, agg16, stats);
    k_final<<<1,256,0,stream>>>(stats, bn_g + l*DD, bn_b + l*DD, stats+2*DD, stats+3*DD);
    k_apply<<<2048,256,0,stream>>>(agg16, stats+2*DD, stats+3*DD, h16);
  }

  gemm_k<2><<<NWG,256,0,stream>>>(h16, wTo, DD, out_b, out, nullptr);
}

// Round 5
// 1301.125 us; speedup vs baseline: 2.2915x; 1.0147x over previous
//
#include <hip/hip_runtime.h>
#include <hip/hip_bf16.h>
#include <stdint.h>

#define NN 50000
#define EE 100000
#define DD 768
#define MP 50176   // 196 * 256
#define KIN 96     // 78 padded to 96
#define SCB 196    // ceil(50000/256) scan blocks

typedef _Float16 half_t;
typedef __attribute__((ext_vector_type(8))) _Float16 v8h;
typedef __attribute__((ext_vector_type(4))) float v4f;

__device__ __forceinline__ void gload16(const half_t* g, half_t* l){
  __builtin_amdgcn_global_load_lds(
      (const __attribute__((address_space(1))) unsigned int*)(g),
      (__attribute__((address_space(3))) unsigned int*)(l),
      16, 0, 0);
}

// ================= 256x256 deep-pipelined GEMM (conv / out-proj) =================
// C[M x 768] = A[M x 768](f16) * Bt[768 x 768]^T(f16)
// 512 threads = 8 waves (2 M-warps x 4 N-warps); BK=32; triple-buffered LDS;
// counted vmcnt(8) pipeline (never drains to 0 in steady state); raw s_barrier.
// MODE 1: conv     -> o16 = f16(acc)        (LDS-transpose epilogue, coalesced)
// MODE 2: out proj -> o32 = acc + bias      (fp32 direct stores, rows < NN)
template<int MODE>
__global__ __launch_bounds__(512, 2)
void gemm256_k(const half_t* __restrict__ A,
               const half_t* __restrict__ Bt,
               int K,
               const float* __restrict__ bias,
               float* __restrict__ o32,
               half_t* __restrict__ o16)
{
  __shared__ __align__(16) half_t lds[3*16384];   // 3 bufs x (A 256x32 | B 256x32) = 96 KB

  // bijective XCD swizzle (m204), col-fastest (3 col-blocks share an A-tile)
  const int nwg = gridDim.x;
  const int q = nwg >> 3, r = nwg & 7;
  const int xcd = blockIdx.x & 7, ii = blockIdx.x >> 3;
  const int L = (xcd < r ? xcd*(q+1) : r*(q+1) + (xcd-r)*q) + ii;
  const int rowb = L / 3, colb = L - rowb*3;
  const int m0 = rowb*256, n0 = colb*256;

  const int t = threadIdx.x, l = t&63, w = t>>6;
  const int wm = w>>2, wn = w&3;       // 2 x 4 warp grid; wave tile = 128 x 64

  v4f acc[8][4];
  #pragma unroll
  for (int i=0;i<8;++i)
    #pragma unroll
    for (int j=0;j<4;++j){ v4f z = {0.f,0.f,0.f,0.f}; acc[i][j]=z; }

  // staging addresses (per-lane constants)
  const int strip = w*2;                       // 16-row strips: this wave covers strip, strip+1
  const int srow  = strip*16 + (l>>2);         // row written by lane (first call)
  const int sch   = ((l&3) ^ ((l>>2)&3))*8;    // pre-swizzled source chunk (halfs)
  const half_t* Asrc = A  + (size_t)(m0 + srow)*K + sch;
  const half_t* Bsrc = Bt + (size_t)(n0 + srow)*K + sch;

  auto STAGE = [&](int kt2, int b){
    half_t* Ab = lds + b*16384;
    half_t* Bb = Ab + 8192;
    const int ko = kt2*32;
    gload16(Asrc + ko,                    Ab + strip*512);
    gload16(Bsrc + ko,                    Bb + strip*512);
    gload16(Asrc + ko + (size_t)16*K,     Ab + strip*512 + 512);
    gload16(Bsrc + ko + (size_t)16*K,     Bb + strip*512 + 512);
  };

  const int nkt = K/32;   // 24 for K=768
  STAGE(0,0); STAGE(1,1); STAGE(2,2);

  // fragment read constants
  const int ra = l&15;
  const int pc = ((l>>4) ^ (l&3))*8;   // physical chunk (involution with stage pre-swizzle)

  int cb = 0;
  for (int kt=0; kt<nkt; ++kt){
    if (kt < nkt-2)      asm volatile("s_waitcnt vmcnt(8)" ::: "memory");
    else if (kt==nkt-2)  asm volatile("s_waitcnt vmcnt(4)" ::: "memory");
    else                 asm volatile("s_waitcnt vmcnt(0)" ::: "memory");
    __builtin_amdgcn_s_barrier();
    asm volatile("" ::: "memory");

    const half_t* Ab = lds + cb*16384;
    const half_t* Bb = Ab + 8192;
    v8h af[8], bf[4];
    #pragma unroll
    for (int n=0;n<4;++n)
      bf[n] = *(const v8h*)(Bb + (wn*64 + n*16 + ra)*32 + pc);
    #pragma unroll
    for (int m=0;m<8;++m)
      af[m] = *(const v8h*)(Ab + (wm*128 + m*16 + ra)*32 + pc);

    __builtin_amdgcn_s_setprio(1);
    #pragma unroll
    for (int m=0;m<8;++m)
      #pragma unroll
      for (int n=0;n<4;++n)
        acc[m][n] = __builtin_amdgcn_mfma_f32_16x16x32_f16(af[m], bf[n], acc[m][n], 0,0,0);
    __builtin_amdgcn_s_setprio(0);

    asm volatile("" ::: "memory");
    __builtin_amdgcn_s_barrier();
    asm volatile("" ::: "memory");

    if (kt+3 < nkt) STAGE(kt+3, cb);
    cb = (cb==2) ? 0 : cb+1;
  }

  if (MODE==2){
    float bv[4];
    #pragma unroll
    for (int n=0;n<4;++n) bv[n] = bias[n0 + wn*64 + n*16 + ra];
    #pragma unroll
    for (int m=0;m<8;++m){
      #pragma unroll
      for (int rr=0;rr<4;++rr){
        int row = m0 + wm*128 + m*16 + (l>>4)*4 + rr;
        if (row >= NN) continue;
        #pragma unroll
        for (int n=0;n<4;++n){
          int col = n0 + wn*64 + n*16 + ra;
          o32[(size_t)row*DD + col] = acc[m][n][rr] + bv[n];
        }
      }
    }
  } else {
    // LDS-transpose epilogue, two 128-row passes (64 KB of lds reused)
    #pragma unroll
    for (int p=0;p<2;++p){
      __syncthreads();
      if (wm==p){
        #pragma unroll
        for (int m=0;m<8;++m)
          #pragma unroll
          for (int rr=0;rr<4;++rr){
            int rw = m*16 + (l>>4)*4 + rr;
            #pragma unroll
            for (int n=0;n<4;++n){
              int col = wn*64 + n*16 + ra;
              lds[rw*256 + (col ^ ((rw&15)<<3))] = (half_t)acc[m][n][rr];
            }
          }
      }
      __syncthreads();
      #pragma unroll
      for (int g=0; g<8; ++g){
        int rw = (t>>5) + g*16;
        int colB = (t&31)*8;
        v8h hv = *(const v8h*)(lds + rw*256 + (colB ^ ((rw&15)<<3)));
        *(v8h*)(o16 + (size_t)(m0 + p*128 + rw)*DD + n0 + colB) = hv;
      }
    }
  }
}

// ================= 128x128 GEMM (input proj, K=96) =================
__global__ __launch_bounds__(256)
void gemm128_k(const half_t* __restrict__ A,
               const half_t* __restrict__ Bt,
               int K,
               const float* __restrict__ bias,
               half_t* __restrict__ o16)
{
  __shared__ __align__(16) half_t smem[128*128];
  half_t* As = smem;
  half_t* Bs = smem + 128*32;
  const int nwg = gridDim.x;
  const int q = nwg >> 3, r = nwg & 7;
  const int xcd = blockIdx.x & 7, ii = blockIdx.x >> 3;
  const int L = (xcd < r ? xcd*(q+1) : r*(q+1) + (xcd-r)*q) + ii;
  const int rowb = L / 6, colb = L - rowb*6;
  const int m0 = rowb*128, n0 = colb*128;

  const int t = threadIdx.x, l = t&63, w = t>>6;
  const int wr = w>>1, wc = w&1;
  v4f acc[4][4];
  #pragma unroll
  for (int i=0;i<4;++i)
    #pragma unroll
    for (int j=0;j<4;++j){ v4f z = {0.f,0.f,0.f,0.f}; acc[i][j]=z; }

  const int nkt = K/32;
  for (int kt=0; kt<nkt; ++kt){
    __syncthreads();
    #pragma unroll
    for (int j=0;j<2;++j){
      int br  = w*32 + j*16;
      int row = br + (l>>2);
      int ch  = (l&3) ^ ((row>>1)&3);
      gload16(A  + (size_t)(m0+row)*K + kt*32 + ch*8, As + br*32);
      gload16(Bt + (size_t)(n0+row)*K + kt*32 + ch*8, Bs + br*32);
    }
    __syncthreads();
    v8h af[4], bf[4];
    #pragma unroll
    for (int m=0;m<4;++m){
      int row = wr*64 + m*16 + (l&15);
      int ch = (l>>4) ^ ((row>>1)&3);
      af[m] = *(const v8h*)(As + row*32 + ch*8);
    }
    #pragma unroll
    for (int n=0;n<4;++n){
      int row = wc*64 + n*16 + (l&15);
      int ch = (l>>4) ^ ((row>>1)&3);
      bf[n] = *(const v8h*)(Bs + row*32 + ch*8);
    }
    #pragma unroll
    for (int m=0;m<4;++m)
      #pragma unroll
      for (int n=0;n<4;++n)
        acc[m][n] = __builtin_amdgcn_mfma_f32_16x16x32_f16(af[m], bf[n], acc[m][n], 0,0,0);
  }

  __syncthreads();
  #pragma unroll
  for (int m=0;m<4;++m){
    #pragma unroll
    for (int rr=0;rr<4;++rr){
      int row = wr*64 + m*16 + (l>>4)*4 + rr;
      #pragma unroll
      for (int n=0;n<4;++n){
        int colL = wc*64 + n*16 + (l&15);
        float v = acc[m][n][rr] + bias[n0+colL];
        int col = colL ^ (((row>>2)&3)<<4);
        smem[row*128 + col] = (half_t)v;
      }
    }
  }
  __syncthreads();
  #pragma unroll
  for (int c=0;c<8;++c){
    int row = c*16 + (t>>4);
    int colBase = (t&15)*8;
    int col = colBase ^ (((row>>2)&3)<<4);
    v8h hv = *(const v8h*)(smem + row*128 + col);
    *(v8h*)(o16 + (size_t)(m0+row)*DD + n0 + colBase) = hv;
  }
}

// ---------------- degree / CSR build ----------------
__global__ void k_count(const int* __restrict__ dst, int* __restrict__ cnt){
  int e = blockIdx.x*256 + threadIdx.x;
  if (e < EE) atomicAdd(&cnt[dst[e]], 1);
}
__global__ void k_dinv(const int* __restrict__ cnt, float* __restrict__ dinv){
  int i = blockIdx.x*256 + threadIdx.x;
  if (i < MP) dinv[i] = (i < NN) ? rsqrtf((float)cnt[i] + 1.0f) : 0.f;
}
__global__ void k_bsum(const int* __restrict__ cnt, int* __restrict__ bsum){
  int i = blockIdx.x*256 + threadIdx.x;
  int v = (i < NN) ? cnt[i] : 0;
  #pragma unroll
  for (int o=1;o<64;o<<=1) v += __shfl_xor(v, o);
  __shared__ int ws_[4];
  if ((threadIdx.x&63)==0) ws_[threadIdx.x>>6] = v;
  __syncthreads();
  if (threadIdx.x==0) bsum[blockIdx.x] = ws_[0]+ws_[1]+ws_[2]+ws_[3];
}
__global__ void k_btop(const int* __restrict__ bsum, int* __restrict__ boff){
  if (threadIdx.x==0){
    int run = 0;
    for (int b=0;b<SCB;++b){ boff[b] = run; run += bsum[b]; }
  }
}
__global__ void k_rowptr(const int* __restrict__ cnt, const int* __restrict__ boff,
                         int* __restrict__ rowptr, int* __restrict__ cursor){
  __shared__ int sh[256];
  int i = blockIdx.x*256 + threadIdx.x;
  int v = (i < NN) ? cnt[i] : 0;
  sh[threadIdx.x] = v; __syncthreads();
  #pragma unroll
  for (int o=1;o<256;o<<=1){
    int add = 0;
    if (threadIdx.x >= o) add = sh[threadIdx.x - o];
    __syncthreads();
    sh[threadIdx.x] += add;
    __syncthreads();
  }
  int excl = sh[threadIdx.x] - v + boff[blockIdx.x];
  if (i <= NN) rowptr[i] = excl;
  if (i < NN)  cursor[i] = excl;
}
__global__ void k_fill(const int* __restrict__ src, const int* __restrict__ dst,
                       const float* __restrict__ dinv, int* __restrict__ cursor,
                       int* __restrict__ ss, float* __restrict__ we){
  int e = blockIdx.x*256 + threadIdx.x;
  if (e < EE){
    int s = src[e], d = dst[e];
    int pos = atomicAdd(&cursor[d], 1);
    ss[pos] = s;
    we[pos] = dinv[s]*dinv[d];
  }
}
__global__ void k_x16(const float* __restrict__ x, half_t* __restrict__ x16){
  int idx = blockIdx.x*256 + threadIdx.x;
  if (idx < MP*KIN){
    int row = idx / KIN, k = idx - row*KIN;
    float v = (row < NN && k < 78) ? x[(size_t)row*78 + k] : 0.f;
    x16[idx] = (half_t)v;
  }
}
__global__ void k_tr(const float* __restrict__ src, half_t* __restrict__ dst, int K, int ldk){
  int idx = blockIdx.x*256 + threadIdx.x;
  if (idx < DD*ldk){
    int n = idx / ldk, k = idx - n*ldk;
    dst[idx] = (k < K) ? (half_t)src[(size_t)k*DD + n] : (half_t)0.f;
  }
}

// ---------------- CSR gather: agg16 = f16(bias + dinv^2*xw[d] + sum en*xw[src]); fused BN stats ----------------
__global__ __launch_bounds__(256)
void k_gather(const int* __restrict__ rowptr, const int* __restrict__ ss,
              const float* __restrict__ we, const half_t* __restrict__ xw,
              const float* __restrict__ dinv, const float* __restrict__ bias,
              half_t* __restrict__ agg16, float* __restrict__ stats){
  const int t = threadIdx.x;
  const float b0 = bias[t], b1 = bias[t+256], b2 = bias[t+512];
  float s0=0,s1=0,s2=0,q0=0,q1=0,q2=0;
  for (int d = blockIdx.x; d < NN; d += gridDim.x){
    int beg = rowptr[d], end = rowptr[d+1];
    float dv = dinv[d], sn = dv*dv;
    const half_t* xr = xw + (size_t)d*DD;
    float a0 = fmaf(sn, (float)xr[t    ], b0);
    float a1 = fmaf(sn, (float)xr[t+256], b1);
    float a2 = fmaf(sn, (float)xr[t+512], b2);
    for (int e=beg; e<end; ++e){
      int s = ss[e]; float wt = we[e];
      const half_t* xs = xw + (size_t)s*DD;
      a0 = fmaf(wt, (float)xs[t    ], a0);
      a1 = fmaf(wt, (float)xs[t+256], a1);
      a2 = fmaf(wt, (float)xs[t+512], a2);
    }
    half_t* ar = agg16 + (size_t)d*DD;
    ar[t] = (half_t)a0; ar[t+256] = (half_t)a1; ar[t+512] = (half_t)a2;
    s0 += a0; q0 += a0*a0;
    s1 += a1; q1 += a1*a1;
    s2 += a2; q2 += a2*a2;
  }
  atomicAdd(&stats[t],        s0); atomicAdd(&stats[t+256],     s1); atomicAdd(&stats[t+512],     s2);
  atomicAdd(&stats[DD+t],     q0); atomicAdd(&stats[DD+t+256],  q1); atomicAdd(&stats[DD+t+512],  q2);
}

__global__ void k_final(const float* __restrict__ stats, const float* __restrict__ g,
                        const float* __restrict__ b, float* __restrict__ sc, float* __restrict__ sh){
  int t = threadIdx.x;
  #pragma unroll
  for (int j=0;j<3;++j){
    int d = t + j*256;
    float mu  = stats[d]      * (1.0f/NN);
    float msq = stats[DD+d]   * (1.0f/NN);
    float var = msq - mu*mu;
    float rstd = rsqrtf(var + 1e-5f);
    float scale = rstd * g[d];
    sc[d] = scale;
    sh[d] = b[d] - mu*scale;
  }
}
// h16 += relu(agg*sc + sh)   (fp16 residual state)
__global__ void k_apply(const half_t* __restrict__ agg16, const float* __restrict__ sc,
                        const float* __restrict__ sh, half_t* __restrict__ h16){
  const int total = NN*DD/8;
  for (int i = blockIdx.x*blockDim.x + threadIdx.x; i < total; i += gridDim.x*blockDim.x){
    size_t base = (size_t)i*8;
    int col = (int)(base % DD);
    v8h a = *(const v8h*)(agg16 + base);
    v8h h = *(const v8h*)(h16 + base);
    v8h o;
    #pragma unroll
    for (int j=0;j<8;++j){
      float v = fmaxf(fmaf((float)a[j], sc[col+j], sh[col+j]), 0.f);
      o[j] = (half_t)((float)h[j] + v);
    }
    *(v8h*)(h16 + base) = o;
  }
}

extern "C" void kernel_launch(void* const* d_in, const int* in_sizes, int n_in,
                              void* d_out, int out_size, void* d_ws, size_t ws_size,
                              hipStream_t stream){
  (void)in_sizes; (void)n_in; (void)out_size; (void)ws_size;
  const float* x      = (const float*)d_in[0];
  const int*   ei     = (const int*)  d_in[1];
  const float* in_w   = (const float*)d_in[2];
  const float* in_b   = (const float*)d_in[3];
  const float* conv_w = (const float*)d_in[4];
  const float* conv_b = (const float*)d_in[5];
  const float* bn_g   = (const float*)d_in[6];
  const float* bn_b   = (const float*)d_in[7];
  const float* out_w  = (const float*)d_in[8];
  const float* out_b  = (const float*)d_in[9];
  float* out = (float*)d_out;
  const int* srcI = ei;
  const int* dstI = ei + EE;

  char* ws = (char*)d_ws; size_t off = 0;
  auto alloc = [&](size_t b)->void*{ void* p = ws + off; off += (b + 255) & ~(size_t)255; return p; };
  half_t* h16  = (half_t*)alloc((size_t)MP*DD*2);
  half_t* xw16 = (half_t*)alloc((size_t)MP*DD*2);
  half_t* agg16= (half_t*)alloc((size_t)NN*DD*2);
  half_t* x16  = (half_t*)alloc((size_t)MP*KIN*2);
  half_t* wT   = (half_t*)alloc((size_t)(DD*KIN + 6*DD*DD)*2);
  float* dinv   = (float*)alloc((size_t)MP*4);
  int*   cnt    = (int*)  alloc((size_t)MP*4);
  int*   rowptr = (int*)  alloc((size_t)(NN+1)*4);
  int*   cursor = (int*)  alloc((size_t)NN*4);
  int*   ssE    = (int*)  alloc((size_t)EE*4);
  float* weE    = (float*)alloc((size_t)EE*4);
  int*   bsum   = (int*)  alloc((size_t)SCB*4);
  int*   boff   = (int*)  alloc((size_t)SCB*4);
  float* stats  = (float*)alloc((size_t)4*DD*4);

  half_t* wTin = wT;
  half_t* wTc  = wT + DD*KIN;
  half_t* wTo  = wTc + 5*DD*DD;

  hipMemsetAsync(cnt, 0, (size_t)MP*4, stream);
  k_count<<<(EE+255)/256,256,0,stream>>>(dstI, cnt);
  k_dinv <<<(MP+255)/256,256,0,stream>>>(cnt, dinv);
  k_bsum <<<SCB,256,0,stream>>>(cnt, bsum);
  k_btop <<<1,64,0,stream>>>(bsum, boff);
  k_rowptr<<<SCB,256,0,stream>>>(cnt, boff, rowptr, cursor);
  k_fill <<<(EE+255)/256,256,0,stream>>>(srcI, dstI, dinv, cursor, ssE, weE);
  k_x16  <<<(MP*KIN+255)/256,256,0,stream>>>(x, x16);
  k_tr   <<<(DD*KIN+255)/256,256,0,stream>>>(in_w, wTin, 78, KIN);
  for (int l = 0; l < 5; ++l)
    k_tr <<<(DD*DD+255)/256,256,0,stream>>>(conv_w + (size_t)l*DD*DD, wTc + (size_t)l*DD*DD, DD, DD);
  k_tr   <<<(DD*DD+255)/256,256,0,stream>>>(out_w, wTo, DD, DD);

  const int NWG1 = (MP/128)*(DD/128);   // 392*6
  gemm128_k<<<NWG1,256,0,stream>>>(x16, wTin, KIN, in_b, h16);

  const int NWG2 = (MP/256)*(DD/256);   // 196*3 = 588
  for (int l = 0; l < 5; ++l){
    gemm256_k<1><<<NWG2,512,0,stream>>>(h16, wTc + (size_t)l*DD*DD, DD, nullptr, nullptr, xw16);
    hipMemsetAsync(stats, 0, (size_t)2*DD*4, stream);
    k_gather<<<2048,256,0,stream>>>(rowptr, ssE, weE, xw16, dinv, conv_b + l*DD, agg16, stats);
    k_final<<<1,256,0,stream>>>(stats, bn_g + l*DD, bn_b + l*DD, stats+2*DD, stats+3*DD);
    k_apply<<<2048,256,0,stream>>>(agg16, stats+2*DD, stats+3*DD, h16);
  }

  gemm256_k<2><<<NWG2,512,0,stream>>>(h16, wTo, DD, out_b, out, nullptr);
}

// Round 6
// 1231.070 us; speedup vs baseline: 2.4219x; 1.0569x over previous
//
#include <hip/hip_runtime.h>
#include <hip/hip_bf16.h>
#include <stdint.h>

#define NN 50000
#define EE 100000
#define DD 768
#define MP 50176   // 196 * 256
#define KIN 96     // 78 padded to 96
#define SCB 196    // ceil(50000/256) scan blocks

typedef _Float16 half_t;
typedef __attribute__((ext_vector_type(8))) _Float16 v8h;
typedef __attribute__((ext_vector_type(4))) float v4f;

__device__ __forceinline__ void gload16(const half_t* g, half_t* l){
  __builtin_amdgcn_global_load_lds(
      (const __attribute__((address_space(1))) unsigned int*)(g),
      (__attribute__((address_space(3))) unsigned int*)(l),
      16, 0, 0);
}

// ================= 256x256 deep-pipelined GEMM, K=768 (conv / out-proj) =================
// 512 threads = 8 waves (2M x 4N); BK=32; triple-buffered LDS (96 KB);
// register-shadow fragment prefetch; ONE barrier per K-step; counted vmcnt(4).
// LDS swizzle: logical chunk c of row r stored at phys chunk c ^ ((r>>1)&3)  (conflict-free)
// MODE 1: conv     -> o16 = f16(acc)        (LDS-transpose epilogue, coalesced)
// MODE 2: out proj -> o32 = acc + bias      (fp32 direct stores, rows < NN)
template<int MODE>
__global__ __launch_bounds__(512, 2)
void gemm256_k(const half_t* __restrict__ A,
               const half_t* __restrict__ Bt,
               const float* __restrict__ bias,
               float* __restrict__ o32,
               half_t* __restrict__ o16)
{
  constexpr int K = 768;
  constexpr int NKT = 24;
  __shared__ __align__(16) half_t lds[3*16384];   // 3 bufs x (A 256x32 | B 256x32)

  // bijective XCD swizzle (m204), col-fastest (3 col-blocks share an A-tile)
  const int nwg = gridDim.x;
  const int q = nwg >> 3, r = nwg & 7;
  const int xcd = blockIdx.x & 7, ii = blockIdx.x >> 3;
  const int L = (xcd < r ? xcd*(q+1) : r*(q+1) + (xcd-r)*q) + ii;
  const int rowb = L / 3, colb = L - rowb*3;
  const int m0 = rowb*256, n0 = colb*256;

  const int t = threadIdx.x, l = t&63, w = t>>6;
  const int wm = w>>2, wn = w&3;       // wave tile = 128 x 64

  v4f acc[8][4];
  #pragma unroll
  for (int i=0;i<8;++i)
    #pragma unroll
    for (int j=0;j<4;++j){ v4f z = {0.f,0.f,0.f,0.f}; acc[i][j]=z; }

  // staging: lane l writes LDS row strip*16+(l>>2), phys chunk l&3 (linear dest);
  // source logical chunk = (l&3) ^ ((row>>1)&3) = (l&3) ^ ((l>>3)&3)
  const int strip = w*2;
  const int srow  = strip*16 + (l>>2);
  const int sch   = ((l&3) ^ ((l>>3)&3))*8;
  const half_t* Asrc = A  + (size_t)(m0 + srow)*K + sch;
  const half_t* Bsrc = Bt + (size_t)(n0 + srow)*K + sch;

  auto STAGE = [&](int kt2, int b){
    half_t* Ab = lds + b*16384;
    half_t* Bb = Ab + 8192;
    const int ko = kt2*32;
    gload16(Asrc + ko,                Ab + strip*512);
    gload16(Bsrc + ko,                Bb + strip*512);
    gload16(Asrc + ko + 16*K,         Ab + strip*512 + 512);
    gload16(Bsrc + ko + 16*K,         Bb + strip*512 + 512);
  };

  // fragment read constants: row = (warp base)+m*16+ra, logical chunk l>>4,
  // phys chunk = (l>>4) ^ ((row>>1)&3) = (l>>4) ^ ((ra>>1)&3)
  const int ra = l&15;
  const int pc = ((l>>4) ^ ((ra>>1)&3))*8;

  v8h af[2][8], bf[2][4];

  #define LOADF(s_, base_) do{                                              \
    const half_t* Ab_ = lds + (base_);                                      \
    const half_t* Bb_ = Ab_ + 8192;                                         \
    _Pragma("unroll")                                                       \
    for (int n_=0;n_<4;++n_) bf[s_][n_] = *(const v8h*)(Bb_ + (wn*64 + n_*16 + ra)*32 + pc); \
    _Pragma("unroll")                                                       \
    for (int m_=0;m_<8;++m_) af[s_][m_] = *(const v8h*)(Ab_ + (wm*128 + m_*16 + ra)*32 + pc); \
  }while(0)

  #define MFMAS(s_) do{                                                     \
    __builtin_amdgcn_s_setprio(1);                                          \
    _Pragma("unroll")                                                       \
    for (int m_=0;m_<8;++m_)                                                \
      _Pragma("unroll")                                                     \
      for (int n_=0;n_<4;++n_)                                              \
        acc[m_][n_] = __builtin_amdgcn_mfma_f32_16x16x32_f16(af[s_][m_], bf[s_][n_], acc[m_][n_], 0,0,0); \
    __builtin_amdgcn_s_setprio(0);                                          \
  }while(0)

  // prologue
  STAGE(0,0); STAGE(1,1); STAGE(2,2);
  asm volatile("s_waitcnt vmcnt(8)" ::: "memory");   // tile 0 landed (this wave)
  __builtin_amdgcn_s_barrier();                      // all waves' tile 0 landed
  LOADF(0, 0);
  asm volatile("s_waitcnt lgkmcnt(0)" ::: "memory");
  __builtin_amdgcn_sched_barrier(0);

  #pragma unroll
  for (int i=0;i<NKT;++i){
    const int cur = i&1, nxt = cur^1;
    if (i < NKT-1){
      if (i < NKT-2) asm volatile("s_waitcnt vmcnt(4)" ::: "memory");  // tile i+1 landed
      else           asm volatile("s_waitcnt vmcnt(0)" ::: "memory");
      __builtin_amdgcn_s_barrier();                  // everyone done reading buf i%3 + tile i+1 visible
      if (i+3 < NKT) STAGE(i+3, i%3);                // overwrite just-consumed buffer
      LOADF(nxt, ((i+1)%3)*16384);                   // ds_read next frags (overlaps MFMA below)
      MFMAS(cur);
      asm volatile("s_waitcnt lgkmcnt(0)" ::: "memory");
      __builtin_amdgcn_sched_barrier(0);             // rule #18: keep next MFMA below the wait
    } else {
      MFMAS(cur);
    }
  }
  #undef LOADF
  #undef MFMAS

  if (MODE==2){
    float bv[4];
    #pragma unroll
    for (int n=0;n<4;++n) bv[n] = bias[n0 + wn*64 + n*16 + ra];
    #pragma unroll
    for (int m=0;m<8;++m){
      #pragma unroll
      for (int rr=0;rr<4;++rr){
        int row = m0 + wm*128 + m*16 + (l>>4)*4 + rr;
        if (row >= NN) continue;
        #pragma unroll
        for (int n=0;n<4;++n){
          int col = n0 + wn*64 + n*16 + ra;
          o32[(size_t)row*DD + col] = acc[m][n][rr] + bv[n];
        }
      }
    }
  } else {
    // LDS-transpose epilogue, two 128-row passes
    #pragma unroll
    for (int p=0;p<2;++p){
      __syncthreads();
      if (wm==p){
        #pragma unroll
        for (int m=0;m<8;++m)
          #pragma unroll
          for (int rr=0;rr<4;++rr){
            int rw = m*16 + (l>>4)*4 + rr;
            #pragma unroll
            for (int n=0;n<4;++n){
              int col = wn*64 + n*16 + ra;
              lds[rw*256 + (col ^ ((rw&15)<<3))] = (half_t)acc[m][n][rr];
            }
          }
      }
      __syncthreads();
      #pragma unroll
      for (int g=0; g<8; ++g){
        int rw = (t>>5) + g*16;
        int colB = (t&31)*8;
        v8h hv = *(const v8h*)(lds + rw*256 + (colB ^ ((rw&15)<<3)));
        *(v8h*)(o16 + (size_t)(m0 + p*128 + rw)*DD + n0 + colB) = hv;
      }
    }
  }
}

// ================= 128x128 GEMM (input proj, K=96) =================
__global__ __launch_bounds__(256)
void gemm128_k(const half_t* __restrict__ A,
               const half_t* __restrict__ Bt,
               int K,
               const float* __restrict__ bias,
               half_t* __restrict__ o16)
{
  __shared__ __align__(16) half_t smem[128*128];
  half_t* As = smem;
  half_t* Bs = smem + 128*32;
  const int nwg = gridDim.x;
  const int q = nwg >> 3, r = nwg & 7;
  const int xcd = blockIdx.x & 7, ii = blockIdx.x >> 3;
  const int L = (xcd < r ? xcd*(q+1) : r*(q+1) + (xcd-r)*q) + ii;
  const int rowb = L / 6, colb = L - rowb*6;
  const int m0 = rowb*128, n0 = colb*128;

  const int t = threadIdx.x, l = t&63, w = t>>6;
  const int wr = w>>1, wc = w&1;
  v4f acc[4][4];
  #pragma unroll
  for (int i=0;i<4;++i)
    #pragma unroll
    for (int j=0;j<4;++j){ v4f z = {0.f,0.f,0.f,0.f}; acc[i][j]=z; }

  const int nkt = K/32;
  for (int kt=0; kt<nkt; ++kt){
    __syncthreads();
    #pragma unroll
    for (int j=0;j<2;++j){
      int br  = w*32 + j*16;
      int row = br + (l>>2);
      int ch  = (l&3) ^ ((row>>1)&3);
      gload16(A  + (size_t)(m0+row)*K + kt*32 + ch*8, As + br*32);
      gload16(Bt + (size_t)(n0+row)*K + kt*32 + ch*8, Bs + br*32);
    }
    __syncthreads();
    v8h af[4], bf[4];
    #pragma unroll
    for (int m=0;m<4;++m){
      int row = wr*64 + m*16 + (l&15);
      int ch = (l>>4) ^ ((row>>1)&3);
      af[m] = *(const v8h*)(As + row*32 + ch*8);
    }
    #pragma unroll
    for (int n=0;n<4;++n){
      int row = wc*64 + n*16 + (l&15);
      int ch = (l>>4) ^ ((row>>1)&3);
      bf[n] = *(const v8h*)(Bs + row*32 + ch*8);
    }
    #pragma unroll
    for (int m=0;m<4;++m)
      #pragma unroll
      for (int n=0;n<4;++n)
        acc[m][n] = __builtin_amdgcn_mfma_f32_16x16x32_f16(af[m], bf[n], acc[m][n], 0,0,0);
  }

  __syncthreads();
  #pragma unroll
  for (int m=0;m<4;++m){
    #pragma unroll
    for (int rr=0;rr<4;++rr){
      int row = wr*64 + m*16 + (l>>4)*4 + rr;
      #pragma unroll
      for (int n=0;n<4;++n){
        int colL = wc*64 + n*16 + (l&15);
        float v = acc[m][n][rr] + bias[n0+colL];
        int col = colL ^ (((row>>2)&3)<<4);
        smem[row*128 + col] = (half_t)v;
      }
    }
  }
  __syncthreads();
  #pragma unroll
  for (int c=0;c<8;++c){
    int row = c*16 + (t>>4);
    int colBase = (t&15)*8;
    int col = colBase ^ (((row>>2)&3)<<4);
    v8h hv = *(const v8h*)(smem + row*128 + col);
    *(v8h*)(o16 + (size_t)(m0+row)*DD + n0 + colBase) = hv;
  }
}

// ---------------- degree / CSR build ----------------
__global__ void k_count(const int* __restrict__ dst, int* __restrict__ cnt){
  int e = blockIdx.x*256 + threadIdx.x;
  if (e < EE) atomicAdd(&cnt[dst[e]], 1);
}
__global__ void k_dinv(const int* __restrict__ cnt, float* __restrict__ dinv){
  int i = blockIdx.x*256 + threadIdx.x;
  if (i < MP) dinv[i] = (i < NN) ? rsqrtf((float)cnt[i] + 1.0f) : 0.f;
}
__global__ void k_bsum(const int* __restrict__ cnt, int* __restrict__ bsum){
  int i = blockIdx.x*256 + threadIdx.x;
  int v = (i < NN) ? cnt[i] : 0;
  #pragma unroll
  for (int o=1;o<64;o<<=1) v += __shfl_xor(v, o);
  __shared__ int ws_[4];
  if ((threadIdx.x&63)==0) ws_[threadIdx.x>>6] = v;
  __syncthreads();
  if (threadIdx.x==0) bsum[blockIdx.x] = ws_[0]+ws_[1]+ws_[2]+ws_[3];
}
__global__ void k_btop(const int* __restrict__ bsum, int* __restrict__ boff){
  if (threadIdx.x==0){
    int run = 0;
    for (int b=0;b<SCB;++b){ boff[b] = run; run += bsum[b]; }
  }
}
__global__ void k_rowptr(const int* __restrict__ cnt, const int* __restrict__ boff,
                         int* __restrict__ rowptr, int* __restrict__ cursor){
  __shared__ int sh[256];
  int i = blockIdx.x*256 + threadIdx.x;
  int v = (i < NN) ? cnt[i] : 0;
  sh[threadIdx.x] = v; __syncthreads();
  #pragma unroll
  for (int o=1;o<256;o<<=1){
    int add = 0;
    if (threadIdx.x >= o) add = sh[threadIdx.x - o];
    __syncthreads();
    sh[threadIdx.x] += add;
    __syncthreads();
  }
  int excl = sh[threadIdx.x] - v + boff[blockIdx.x];
  if (i <= NN) rowptr[i] = excl;
  if (i < NN)  cursor[i] = excl;
}
__global__ void k_fill(const int* __restrict__ src, const int* __restrict__ dst,
                       const float* __restrict__ dinv, int* __restrict__ cursor,
                       int* __restrict__ ss, float* __restrict__ we){
  int e = blockIdx.x*256 + threadIdx.x;
  if (e < EE){
    int s = src[e], d = dst[e];
    int pos = atomicAdd(&cursor[d], 1);
    ss[pos] = s;
    we[pos] = dinv[s]*dinv[d];
  }
}
__global__ void k_x16(const float* __restrict__ x, half_t* __restrict__ x16){
  int idx = blockIdx.x*256 + threadIdx.x;
  if (idx < MP*KIN){
    int row = idx / KIN, k = idx - row*KIN;
    float v = (row < NN && k < 78) ? x[(size_t)row*78 + k] : 0.f;
    x16[idx] = (half_t)v;
  }
}
__global__ void k_tr(const float* __restrict__ src, half_t* __restrict__ dst, int K, int ldk){
  int idx = blockIdx.x*256 + threadIdx.x;
  if (idx < DD*ldk){
    int n = idx / ldk, k = idx - n*ldk;
    dst[idx] = (k < K) ? (half_t)src[(size_t)k*DD + n] : (half_t)0.f;
  }
}

// ---------------- CSR gather: agg16 = f16(bias + dinv^2*xw[d] + sum en*xw[src]); fused BN stats ----------------
__global__ __launch_bounds__(256)
void k_gather(const int* __restrict__ rowptr, const int* __restrict__ ss,
              const float* __restrict__ we, const half_t* __restrict__ xw,
              const float* __restrict__ dinv, const float* __restrict__ bias,
              half_t* __restrict__ agg16, float* __restrict__ stats){
  const int t = threadIdx.x;
  const float b0 = bias[t], b1 = bias[t+256], b2 = bias[t+512];
  float s0=0,s1=0,s2=0,q0=0,q1=0,q2=0;
  for (int d = blockIdx.x; d < NN; d += gridDim.x){
    int beg = rowptr[d], end = rowptr[d+1];
    float dv = dinv[d], sn = dv*dv;
    const half_t* xr = xw + (size_t)d*DD;
    float a0 = fmaf(sn, (float)xr[t    ], b0);
    float a1 = fmaf(sn, (float)xr[t+256], b1);
    float a2 = fmaf(sn, (float)xr[t+512], b2);
    for (int e=beg; e<end; ++e){
      int s = ss[e]; float wt = we[e];
      const half_t* xs = xw + (size_t)s*DD;
      a0 = fmaf(wt, (float)xs[t    ], a0);
      a1 = fmaf(wt, (float)xs[t+256], a1);
      a2 = fmaf(wt, (float)xs[t+512], a2);
    }
    half_t* ar = agg16 + (size_t)d*DD;
    ar[t] = (half_t)a0; ar[t+256] = (half_t)a1; ar[t+512] = (half_t)a2;
    s0 += a0; q0 += a0*a0;
    s1 += a1; q1 += a1*a1;
    s2 += a2; q2 += a2*a2;
  }
  atomicAdd(&stats[t],        s0); atomicAdd(&stats[t+256],     s1); atomicAdd(&stats[t+512],     s2);
  atomicAdd(&stats[DD+t],     q0); atomicAdd(&stats[DD+t+256],  q1); atomicAdd(&stats[DD+t+512],  q2);
}

__global__ void k_final(const float* __restrict__ stats, const float* __restrict__ g,
                        const float* __restrict__ b, float* __restrict__ sc, float* __restrict__ sh){
  int t = threadIdx.x;
  #pragma unroll
  for (int j=0;j<3;++j){
    int d = t + j*256;
    float mu  = stats[d]      * (1.0f/NN);
    float msq = stats[DD+d]   * (1.0f/NN);
    float var = msq - mu*mu;
    float rstd = rsqrtf(var + 1e-5f);
    float scale = rstd * g[d];
    sc[d] = scale;
    sh[d] = b[d] - mu*scale;
  }
}
// h16 += relu(agg*sc + sh)   (fp16 residual state)
__global__ void k_apply(const half_t* __restrict__ agg16, const float* __restrict__ sc,
                        const float* __restrict__ sh, half_t* __restrict__ h16){
  const int total = NN*DD/8;
  for (int i = blockIdx.x*blockDim.x + threadIdx.x; i < total; i += gridDim.x*blockDim.x){
    size_t base = (size_t)i*8;
    int col = (int)(base % DD);
    v8h a = *(const v8h*)(agg16 + base);
    v8h h = *(const v8h*)(h16 + base);
    v8h o;
    #pragma unroll
    for (int j=0;j<8;++j){
      float v = fmaxf(fmaf((float)a[j], sc[col+j], sh[col+j]), 0.f);
      o[j] = (half_t)((float)h[j] + v);
    }
    *(v8h*)(h16 + base) = o;
  }
}

extern "C" void kernel_launch(void* const* d_in, const int* in_sizes, int n_in,
                              void* d_out, int out_size, void* d_ws, size_t ws_size,
                              hipStream_t stream){
  (void)in_sizes; (void)n_in; (void)out_size; (void)ws_size;
  const float* x      = (const float*)d_in[0];
  const int*   ei     = (const int*)  d_in[1];
  const float* in_w   = (const float*)d_in[2];
  const float* in_b   = (const float*)d_in[3];
  const float* conv_w = (const float*)d_in[4];
  const float* conv_b = (const float*)d_in[5];
  const float* bn_g   = (const float*)d_in[6];
  const float* bn_b   = (const float*)d_in[7];
  const float* out_w  = (const float*)d_in[8];
  const float* out_b  = (const float*)d_in[9];
  float* out = (float*)d_out;
  const int* srcI = ei;
  const int* dstI = ei + EE;

  char* ws = (char*)d_ws; size_t off = 0;
  auto alloc = [&](size_t b)->void*{ void* p = ws + off; off += (b + 255) & ~(size_t)255; return p; };
  half_t* h16  = (half_t*)alloc((size_t)MP*DD*2);
  half_t* xw16 = (half_t*)alloc((size_t)MP*DD*2);
  half_t* agg16= (half_t*)alloc((size_t)NN*DD*2);
  half_t* x16  = (half_t*)alloc((size_t)MP*KIN*2);
  half_t* wT   = (half_t*)alloc((size_t)(DD*KIN + 6*DD*DD)*2);
  float* dinv   = (float*)alloc((size_t)MP*4);
  int*   cnt    = (int*)  alloc((size_t)MP*4);
  int*   rowptr = (int*)  alloc((size_t)(NN+1)*4);
  int*   cursor = (int*)  alloc((size_t)NN*4);
  int*   ssE    = (int*)  alloc((size_t)EE*4);
  float* weE    = (float*)alloc((size_t)EE*4);
  int*   bsum   = (int*)  alloc((size_t)SCB*4);
  int*   boff   = (int*)  alloc((size_t)SCB*4);
  float* stats  = (float*)alloc((size_t)4*DD*4);

  half_t* wTin = wT;
  half_t* wTc  = wT + DD*KIN;
  half_t* wTo  = wTc + 5*DD*DD;

  hipMemsetAsync(cnt, 0, (size_t)MP*4, stream);
  k_count<<<(EE+255)/256,256,0,stream>>>(dstI, cnt);
  k_dinv <<<(MP+255)/256,256,0,stream>>>(cnt, dinv);
  k_bsum <<<SCB,256,0,stream>>>(cnt, bsum);
  k_btop <<<1,64,0,stream>>>(bsum, boff);
  k_rowptr<<<SCB,256,0,stream>>>(cnt, boff, rowptr, cursor);
  k_fill <<<(EE+255)/256,256,0,stream>>>(srcI, dstI, dinv, cursor, ssE, weE);
  k_x16  <<<(MP*KIN+255)/256,256,0,stream>>>(x, x16);
  k_tr   <<<(DD*KIN+255)/256,256,0,stream>>>(in_w, wTin, 78, KIN);
  for (int l = 0; l < 5; ++l)
    k_tr <<<(DD*DD+255)/256,256,0,stream>>>(conv_w + (size_t)l*DD*DD, wTc + (size_t)l*DD*DD, DD, DD);
  k_tr   <<<(DD*DD+255)/256,256,0,stream>>>(out_w, wTo, DD, DD);

  const int NWG1 = (MP/128)*(DD/128);
  gemm128_k<<<NWG1,256,0,stream>>>(x16, wTin, KIN, in_b, h16);

  const int NWG2 = (MP/256)*(DD/256);   // 196*3 = 588
  for (int l = 0; l < 5; ++l){
    gemm256_k<1><<<NWG2,512,0,stream>>>(h16, wTc + (size_t)l*DD*DD, nullptr, nullptr, xw16);
    hipMemsetAsync(stats, 0, (size_t)2*DD*4, stream);
    k_gather<<<2048,256,0,stream>>>(rowptr, ssE, weE, xw16, dinv, conv_b + l*DD, agg16, stats);
    k_final<<<1,256,0,stream>>>(stats, bn_g + l*DD, bn_b + l*DD, stats+2*DD, stats+3*DD);
    k_apply<<<2048,256,0,stream>>>(agg16, stats+2*DD, stats+3*DD, h16);
  }

  gemm256_k<2><<<NWG2,512,0,stream>>>(h16, wTo, out_b, out, nullptr);
}